// Round 16
// baseline (191.565 us; speedup 1.0000x reference)
//
#include <hip/hip_runtime.h>
#include <hip/hip_bf16.h>
#include <math.h>

#define NPOS 32768      // 32*32*32
#define CCH  128
#define C3   384
#define CF   512
#define NSH  16         // IN1 stats shadow copies
#define NSH2 32         // IN2 stats shadow copies (grid 1024 -> keep 32-way)

typedef __attribute__((ext_vector_type(8))) short short8;
typedef __attribute__((ext_vector_type(4))) float f32x4;

__device__ inline float bf2f(unsigned short u) {
    union { unsigned int i; float f; } x; x.i = ((unsigned int)u) << 16; return x.f;
}
__device__ inline unsigned short f2bf(float f) {
    union { float f; unsigned int i; } x; x.f = f;
    unsigned int r = x.i + 0x7FFFu + ((x.i >> 16) & 1u);   // round-nearest-even
    return (unsigned short)(r >> 16);
}
__device__ inline float lo_bf(unsigned int u) {
    union { unsigned int i; float f; } x; x.i = u << 16; return x.f;
}
__device__ inline float hi_bf(unsigned int u) {
    union { unsigned int i; float f; } x; x.i = u & 0xffff0000u; return x.f;
}

// ---------------------------------------------------------------------------
// qkv FUSED kernel (R12; zeroing extended to 24*512 stats floats)
// ---------------------------------------------------------------------------
__global__ __launch_bounds__(256) void qkv_fused_kernel(
    const float* __restrict__ x,        // (128, 32768) fp32
    const float* __restrict__ wqkv,     // (384, 128) fp32
    const float* __restrict__ b_qkv,
    const float* __restrict__ wp,  const float* __restrict__ w1f,
    const float* __restrict__ w2f,
    unsigned short* __restrict__ wp_b, unsigned short* __restrict__ w1_b,
    unsigned short* __restrict__ w2_b,
    float* __restrict__ stats,
    unsigned short* __restrict__ outh)  // (24, N, 16) bf16 head-major
{
    __shared__ alignas(16) unsigned short As[128 * 136];   // [n][c] bf16
    __shared__ alignas(16) unsigned short Bs[128 * 136];   // [col][c] bf16

    const int tid  = threadIdx.x;
    const int lane = tid & 63;
    const int wave = tid >> 6;
    const int wm = wave & 1, wn = wave >> 1;
    const int row0 = blockIdx.y * 128;
    const int col0 = blockIdx.x * 128;

    if (blockIdx.x == 0) {
        if (blockIdx.y < 24) {   // zero 12288 stat floats (16 IN1 + 32 IN2 banks)
            stats[blockIdx.y * 512 + tid] = 0.f;
            stats[blockIdx.y * 512 + 256 + tid] = 0.f;
        }
        if (tid < 144) {
            const int ci = blockIdx.y * 144 + tid;   // 0..36863 float4s
            const float* src; unsigned short* dst; int off;
            if (ci < 4096)       { src = wp;  dst = wp_b; off = ci; }
            else if (ci < 20480) { src = w1f; dst = w1_b; off = ci - 4096; }
            else                 { src = w2f; dst = w2_b; off = ci - 20480; }
            const float4 v = ((const float4*)src)[off];
            ushort4 o;
            o.x = f2bf(v.x); o.y = f2bf(v.y); o.z = f2bf(v.z); o.w = f2bf(v.w);
            ((ushort4*)dst)[off] = o;
        }
    }

    #pragma unroll
    for (int it = 0; it < 16; ++it) {
        const int idx = tid + it * 256;
        const int c  = idx >> 5;
        const int nq = idx & 31;
        const float4 v = *(const float4*)&x[(size_t)c * NPOS + row0 + nq * 4];
        As[(nq * 4 + 0) * 136 + c] = f2bf(v.x);
        As[(nq * 4 + 1) * 136 + c] = f2bf(v.y);
        As[(nq * 4 + 2) * 136 + c] = f2bf(v.z);
        As[(nq * 4 + 3) * 136 + c] = f2bf(v.w);
    }
    #pragma unroll
    for (int it = 0; it < 16; ++it) {
        const int idx = tid + it * 256;
        const int col = idx >> 5;
        const int cq  = idx & 31;
        const float4 v = *(const float4*)&wqkv[(size_t)(col0 + col) * CCH + cq * 4];
        ushort4 o;
        o.x = f2bf(v.x); o.y = f2bf(v.y); o.z = f2bf(v.z); o.w = f2bf(v.w);
        *(ushort4*)&Bs[col * 136 + cq * 4] = o;
    }
    __syncthreads();

    const f32x4 fzero = {0.f, 0.f, 0.f, 0.f};
    f32x4 acc[4][4];
    #pragma unroll
    for (int i = 0; i < 4; ++i)
        #pragma unroll
        for (int j = 0; j < 4; ++j) acc[i][j] = fzero;

    const int lr = lane & 15;
    const int lk = (lane >> 4) * 8;

    #pragma unroll
    for (int ks = 0; ks < 4; ++ks) {
        short8 af[4], bfr[4];
        #pragma unroll
        for (int i = 0; i < 4; ++i)
            af[i]  = *(const short8*)&As[(wm * 64 + i * 16 + lr) * 136 + ks * 32 + lk];
        #pragma unroll
        for (int j = 0; j < 4; ++j)
            bfr[j] = *(const short8*)&Bs[(wn * 64 + j * 16 + lr) * 136 + ks * 32 + lk];
        #pragma unroll
        for (int i = 0; i < 4; ++i)
            #pragma unroll
            for (int j = 0; j < 4; ++j)
                acc[i][j] = __builtin_amdgcn_mfma_f32_16x16x32_bf16(
                                af[i], bfr[j], acc[i][j], 0, 0, 0);
    }

    const int gr0 = row0 + wm * 64 + (lane >> 4) * 4;
    const int gc0 = col0 + wn * 64 + lr;
    #pragma unroll
    for (int j = 0; j < 4; ++j) {
        const int gc  = gc0 + j * 16;
        const int sel = gc >> 4;
        const int ch  = gc & 15;
        const float bv = b_qkv[gc];
        #pragma unroll
        for (int i = 0; i < 4; ++i) {
            #pragma unroll
            for (int r = 0; r < 4; ++r) {
                const int gr = gr0 + i * 16 + r;
                outh[((size_t)sel * NPOS + gr) * 16 + ch] = f2bf(acc[i][j][r] + bv);
            }
        }
    }
}

// ---------------------------------------------------------------------------
// Tiled neighborhood attention (exact R12: head-major input, wave-parallel
// softmax, NO swizzle — swizzle proven harmful in R15)
// ---------------------------------------------------------------------------
__global__ __launch_bounds__(256) void attn_tiled(
    const unsigned short* __restrict__ qkv,   // (24, N, 16) bf16 head-major
    const float* __restrict__ rpb,
    unsigned short* __restrict__ out)
{
    __shared__ unsigned int ksu[288 * 8];
    __shared__ unsigned int vsu[288 * 8];
    __shared__ unsigned int qsu[32 * 8];
    __shared__ float logits[32 * 29];
    __shared__ float rpbs[125];
    __shared__ float sinv[32];

    const int t  = threadIdx.x;
    const int line = ((blockIdx.x & 7) << 7) + (blockIdx.x >> 3);
    const int h  = blockIdx.y;
    const int w0 = line & 31, h0 = line >> 5;
    const int n0 = (h0 << 10) + (w0 << 5);
    const int sh0 = min(max(h0 - 1, 0), 29);
    const int sw0 = min(max(w0 - 1, 0), 29);
    const int rh_off = sh0 - h0 + 2;
    const int rw_off = sw0 - w0 + 2;

    if (t < 64) {
        const int pos = t >> 1, part = t & 1;
        const uint4 raw = *(const uint4*)&qkv[((size_t)h * NPOS + n0 + pos) * 16 + part * 8];
        *(uint4*)&qsu[pos * 8 + part * 4] = raw;
    } else if (t < 192) {
        const int i = t - 64;
        if (i < 125) rpbs[i] = rpb[h * 125 + i];
    }
    for (int c = t; c < 1152; c += 256) {
        const int p = c >> 2, part = c & 3;
        const int ihw = p >> 5, z = p & 31;
        const int ih = (ihw * 11) >> 5;
        const int iw = ihw - 3 * ih;
        const int n = ((sh0 + ih) << 10) + ((sw0 + iw) << 5) + z;
        const int kv = part >> 1;              // 0 = K, 1 = V
        const uint4 raw = *(const uint4*)&qkv[((size_t)(8 + kv * 8 + h) * NPOS + n) * 16
                                              + (part & 1) * 8];
        unsigned int* d = ((kv == 0) ? ksu : vsu) + p * 8 + (part & 1) * 4;
        *(uint4*)d = raw;
    }
    __syncthreads();

    {
        const int q = t >> 3, j = t & 7;
        const int sz = min(max(q - 1, 0), 29);
        const int rz_off = sz - q + 2;
        float qf[16];
        #pragma unroll
        for (int d2 = 0; d2 < 8; ++d2) {
            const unsigned int u = qsu[q * 8 + d2];
            qf[2 * d2] = lo_bf(u); qf[2 * d2 + 1] = hi_bf(u);
        }
        float lv[4];
        int nkk = 0;
        for (int kk = j; kk < 27; kk += 8) {
            const int ihw = kk / 3, dz = kk - 3 * ihw;
            const int ih = ihw / 3,  iw = ihw - 3 * ih;
            const int p = ihw * 32 + sz + dz;
            float a = 0.f;
            #pragma unroll
            for (int d2 = 0; d2 < 8; ++d2) {
                const unsigned int u = ksu[p * 8 + d2];
                a += qf[2 * d2] * lo_bf(u) + qf[2 * d2 + 1] * hi_bf(u);
            }
            const int bidx = ((ih + rh_off) * 5 + (iw + rw_off)) * 5 + (dz + rz_off);
            lv[nkk++] = a * 0.25f + rpbs[bidx];
        }
        float mx = -1e30f;
        #pragma unroll
        for (int u = 0; u < 4; ++u) if (u < nkk) mx = fmaxf(mx, lv[u]);
        mx = fmaxf(mx, __shfl_xor(mx, 1));
        mx = fmaxf(mx, __shfl_xor(mx, 2));
        mx = fmaxf(mx, __shfl_xor(mx, 4));
        float s = 0.f;
        int u = 0;
        for (int kk = j; kk < 27; kk += 8) {
            const float e = __expf(lv[u++] - mx);
            logits[q * 29 + kk] = e;
            s += e;
        }
        s += __shfl_xor(s, 1);
        s += __shfl_xor(s, 2);
        s += __shfl_xor(s, 4);
        if (j == 0) sinv[q] = 1.f / s;
    }
    __syncthreads();

    {
        const int q = t >> 3, d2 = t & 7;
        const int sz = min(max(q - 1, 0), 29);
        float ax = 0.f, ay = 0.f;
        #pragma unroll
        for (int kk = 0; kk < 27; ++kk) {
            const int p = (kk / 3) * 32 + sz + (kk % 3);
            const float w = logits[q * 29 + kk];
            const unsigned int u = vsu[p * 8 + d2];
            ax += w * lo_bf(u); ay += w * hi_bf(u);
        }
        const float inv = sinv[q];
        const unsigned int o = ((unsigned int)f2bf(ay * inv) << 16)
                             |  (unsigned int)f2bf(ax * inv);
        *(unsigned int*)&out[(size_t)(n0 + q) * CCH + h * 16 + d2 * 2] = o;
    }
}

// ---------------------------------------------------------------------------
// K1: proj GEMM (K=128) + bias -> x5 (bf16) + IN1 stats (16-shadow banks)
// (unchanged from R12)
// ---------------------------------------------------------------------------
__global__ __launch_bounds__(256) void proj_stats_kernel(
    const unsigned short* __restrict__ attnO,   // (N,128) bf16
    const unsigned short* __restrict__ wproj,   // (128,128) bf16
    const float* __restrict__ b_proj,
    unsigned short* __restrict__ x5b,           // (N,128) bf16 out
    float* __restrict__ stats)                  // [s*256 + {c,128+c}], s<16 : IN1
{
    __shared__ float red[256];

    const int t    = threadIdx.x;
    const int lane = t & 63;
    const int wn   = t >> 6;
    const int lr = lane & 15;
    const int lg = lane >> 4;
    const int lk = lg * 8;
    const int n0 = blockIdx.x * 64;
    const int sh = (blockIdx.x & (NSH - 1)) * 256;

    red[t] = 0.f;

    short8 wf[2][4];
    #pragma unroll
    for (int j = 0; j < 2; ++j)
        #pragma unroll
        for (int ks = 0; ks < 4; ++ks)
            wf[j][ks] = *(const short8*)&wproj[(wn * 32 + j * 16 + lr) * CCH + ks * 32 + lk];

    const f32x4 fzero = {0.f, 0.f, 0.f, 0.f};
    f32x4 acc[4][2];
    #pragma unroll
    for (int i = 0; i < 4; ++i)
        #pragma unroll
        for (int j = 0; j < 2; ++j) acc[i][j] = fzero;

    #pragma unroll
    for (int ks = 0; ks < 4; ++ks) {
        short8 af[4];
        #pragma unroll
        for (int i = 0; i < 4; ++i)
            af[i] = *(const short8*)&attnO[(size_t)(n0 + i * 16 + lr) * CCH + ks * 32 + lk];
        #pragma unroll
        for (int i = 0; i < 4; ++i)
            #pragma unroll
            for (int j = 0; j < 2; ++j)
                acc[i][j] = __builtin_amdgcn_mfma_f32_16x16x32_bf16(
                                af[i], wf[j][ks], acc[i][j], 0, 0, 0);
    }
    __syncthreads();   // red[] zeroed before atomics

    #pragma unroll
    for (int j = 0; j < 2; ++j) {
        const int gc = wn * 32 + j * 16 + lr;
        const float bv = b_proj[gc];
        float s = 0.f, q = 0.f;
        #pragma unroll
        for (int i = 0; i < 4; ++i)
            #pragma unroll
            for (int r = 0; r < 4; ++r) {
                const int gr = i * 16 + lg * 4 + r;
                const float v = acc[i][j][r] + bv;
                s += v; q += v * v;
                x5b[(size_t)(n0 + gr) * CCH + gc] = f2bf(v);
            }
        atomicAdd(&red[gc], s);
        atomicAdd(&red[128 + gc], q);
    }
    __syncthreads();
    if (t < 128) {
        atomicAdd(&stats[sh + t],       red[t]);
        atomicAdd(&stats[sh + 128 + t], red[128 + t]);
    }
}

// ---------------------------------------------------------------------------
// K2: IN1-normalize -> FFN (4 chunks) -> +residual -> IN2 stats (32-shadow)
//     -> transpose -> tTb (C,N) bf16.
// THIS ROUND: 32 rows/block, grid 1024, LDS 19.4 KB -> 4 blocks/CU ->
// 16 waves/CU (50% cap, was 2 blocks -> 19%). Atomic contention stays 32-way
// via 32 IN2 shadow banks.
// ---------------------------------------------------------------------------
__global__ __launch_bounds__(256) void ffn_fused_kernel(
    const unsigned short* __restrict__ x5b,     // (N,128) bf16
    const unsigned short* __restrict__ w1,      // (512,128) bf16
    const float* __restrict__ b1,
    const unsigned short* __restrict__ w2,      // (128,512) bf16
    const float* __restrict__ b2,
    float* __restrict__ stats,                  // [0:4096) IN1, [4096:12288) IN2 (32 banks)
    unsigned short* __restrict__ tTb)           // (128, 32768) bf16 out
{
    __shared__ alignas(16) unsigned short pool[2 * 4352];   // As | Hs (32x136 shorts each)
    unsigned short* As = pool;
    unsigned short* Hs = pool + 4352;
    __shared__ float red[256];
    __shared__ float ms[128];
    __shared__ float rss[128];

    const int t    = threadIdx.x;
    const int lane = t & 63;
    const int wn   = t >> 6;
    const int lr = lane & 15;
    const int lg = lane >> 4;
    const int lk = lg * 8;
    const int n0 = blockIdx.x * 32;
    const int sh = (blockIdx.x & (NSH2 - 1)) * 256;
    const float invN = 1.f / (float)NPOS;
    const f32x4 fzero = {0.f, 0.f, 0.f, 0.f};

    // ---- Phase A: IN1 factors (sum 16 shadows) + x5 tile load
    red[t] = 0.f;
    if (t < 128) {
        float s0 = 0.f, s1 = 0.f;
        #pragma unroll
        for (int s = 0; s < NSH; ++s) {
            s0 += stats[s * 256 + t];
            s1 += stats[s * 256 + 128 + t];
        }
        const float m = s0 * invN;
        const float v = s1 * invN - m * m;
        ms[t]  = m;
        rss[t] = rsqrtf(v + 1e-5f);
    }
    uint4 px[2];
    #pragma unroll
    for (int it = 0; it < 2; ++it) {
        const int idx = t + it * 256;
        const int row = idx >> 4, c0 = (idx & 15) * 8;
        px[it] = *(const uint4*)&x5b[(size_t)(n0 + row) * CCH + c0];
    }
    __syncthreads();

    // ---- Phase B: normalize -> As (x5n, bf16)
    #pragma unroll
    for (int it = 0; it < 2; ++it) {
        const int idx = t + it * 256;
        const int row = idx >> 4, c0 = (idx & 15) * 8;
        unsigned int u[4] = {px[it].x, px[it].y, px[it].z, px[it].w};
        #pragma unroll
        for (int p = 0; p < 4; ++p) {
            const int c = c0 + 2 * p;
            const float a = (lo_bf(u[p]) - ms[c])     * rss[c];
            const float b = (hi_bf(u[p]) - ms[c + 1]) * rss[c + 1];
            u[p] = ((unsigned int)f2bf(b) << 16) | (unsigned int)f2bf(a);
        }
        uint4 w; w.x = u[0]; w.y = u[1]; w.z = u[2]; w.w = u[3];
        *(uint4*)&As[row * 136 + c0] = w;
    }
    __syncthreads();   // As ready (read-only until Phase E)

    f32x4 acc[2][2];
    #pragma unroll
    for (int i = 0; i < 2; ++i)
        #pragma unroll
        for (int j = 0; j < 2; ++j) acc[i][j] = fzero;

    // ---- Phase C: 4 chunks of 128 hidden cols
    #pragma unroll 1
    for (int cc = 0; cc < 4; ++cc) {
        short8 w1f[2][4];
        #pragma unroll
        for (int j = 0; j < 2; ++j)
            #pragma unroll
            for (int ks = 0; ks < 4; ++ks)
                w1f[j][ks] = *(const short8*)&w1[
                    (size_t)(cc * 128 + wn * 32 + j * 16 + lr) * CCH + ks * 32 + lk];

        f32x4 hacc[2][2];
        #pragma unroll
        for (int i = 0; i < 2; ++i)
            #pragma unroll
            for (int j = 0; j < 2; ++j) hacc[i][j] = fzero;
        #pragma unroll
        for (int ks = 0; ks < 4; ++ks) {
            short8 af[2];
            #pragma unroll
            for (int i = 0; i < 2; ++i)
                af[i] = *(const short8*)&As[(i * 16 + lr) * 136 + ks * 32 + lk];
            #pragma unroll
            for (int i = 0; i < 2; ++i)
                #pragma unroll
                for (int j = 0; j < 2; ++j)
                    hacc[i][j] = __builtin_amdgcn_mfma_f32_16x16x32_bf16(
                                    af[i], w1f[j][ks], hacc[i][j], 0, 0, 0);
        }

        short8 w2f[2][4];
        #pragma unroll
        for (int j = 0; j < 2; ++j)
            #pragma unroll
            for (int ks = 0; ks < 4; ++ks)
                w2f[j][ks] = *(const short8*)&w2[
                    (size_t)(wn * 32 + j * 16 + lr) * CF + cc * 128 + ks * 32 + lk];

        #pragma unroll
        for (int j = 0; j < 2; ++j) {
            const int gc = wn * 32 + j * 16 + lr;
            const float bv = b1[cc * 128 + gc];
            #pragma unroll
            for (int i = 0; i < 2; ++i)
                #pragma unroll
                for (int r = 0; r < 4; ++r) {
                    float v = hacc[i][j][r] + bv;
                    const float g = 0.7978845608028654f * (v + 0.044715f * v * v * v);
                    const float e = __expf(2.f * g);
                    v = v * (e / (e + 1.f));
                    Hs[(i * 16 + lg * 4 + r) * 136 + gc] = f2bf(v);
                }
        }
        __syncthreads();   // Hs ready

        #pragma unroll
        for (int ks = 0; ks < 4; ++ks) {
            short8 af[2];
            #pragma unroll
            for (int i = 0; i < 2; ++i)
                af[i] = *(const short8*)&Hs[(i * 16 + lr) * 136 + ks * 32 + lk];
            #pragma unroll
            for (int i = 0; i < 2; ++i)
                #pragma unroll
                for (int j = 0; j < 2; ++j)
                    acc[i][j] = __builtin_amdgcn_mfma_f32_16x16x32_bf16(
                                    af[i], w2f[j][ks], acc[i][j], 0, 0, 0);
        }
        __syncthreads();   // Hs consumed
    }

    // ---- Phase D: + b2 + residual(x5n), IN2 stats partials
    #pragma unroll
    for (int j = 0; j < 2; ++j) {
        const int gc = wn * 32 + j * 16 + lr;
        const float bv = b2[gc];
        float s = 0.f, q = 0.f;
        #pragma unroll
        for (int i = 0; i < 2; ++i)
            #pragma unroll
            for (int r = 0; r < 4; ++r) {
                const int gr = i * 16 + lg * 4 + r;
                const float v = acc[i][j][r] + bv + bf2f(As[gr * 136 + gc]);
                acc[i][j][r] = v;
                s += v; q += v * v;
            }
        atomicAdd(&red[gc], s);
        atomicAdd(&red[128 + gc], q);
    }
    __syncthreads();
    if (t < 128) {
        atomicAdd(&stats[4096 + sh + t],       red[t]);
        atomicAdd(&stats[4096 + sh + 128 + t], red[128 + t]);
    }

    // ---- Phase E: LDS transpose (overlay) -> tTb (C,N) bf16
    float* tr = (float*)pool;        // 128 x 33 fp32 = 16896 B <= 17408 B pool
    #pragma unroll
    for (int j = 0; j < 2; ++j) {
        const int gc = wn * 32 + j * 16 + lr;
        #pragma unroll
        for (int i = 0; i < 2; ++i)
            #pragma unroll
            for (int r = 0; r < 4; ++r) {
                const int gr = i * 16 + lg * 4 + r;
                tr[gc * 33 + gr] = acc[i][j][r];
            }
    }
    __syncthreads();
    #pragma unroll
    for (int it = 0; it < 4; ++it) {
        const int idx = t + it * 256;
        const int c = idx >> 3, ch = (idx & 7) * 4;
        ushort4 o4;
        o4.x = f2bf(tr[c * 33 + ch + 0]);
        o4.y = f2bf(tr[c * 33 + ch + 1]);
        o4.z = f2bf(tr[c * 33 + ch + 2]);
        o4.w = f2bf(tr[c * 33 + ch + 3]);
        *(ushort4*)&tTb[(size_t)c * NPOS + n0 + ch] = o4;
    }
}

// ---------------------------------------------------------------------------
// K3: IN2 elementwise normalize, bf16 (C,N) in -> fp32 (C,N) out (32 shadows)
// ---------------------------------------------------------------------------
__global__ __launch_bounds__(256) void norm2_apply_kernel(
    const unsigned short* __restrict__ tTb, const float* __restrict__ stats,
    float* __restrict__ out)
{
    const int i = blockIdx.x * 256 + threadIdx.x;
    const size_t o = (size_t)i * 8;
    const int c = (int)(o >> 15);
    const float invN = 1.f / (float)NPOS;
    float s0 = 0.f, s1 = 0.f;
    #pragma unroll
    for (int s = 0; s < NSH2; ++s) {
        s0 += stats[4096 + s * 256 + c];
        s1 += stats[4096 + s * 256 + 128 + c];
    }
    const float m  = s0 * invN;
    const float vr = s1 * invN - m * m;
    const float rs = rsqrtf(vr + 1e-5f);
    const uint4 raw = *(const uint4*)&tTb[o];
    const unsigned int u[4] = {raw.x, raw.y, raw.z, raw.w};
    float4 o0, o1;
    o0.x = (lo_bf(u[0]) - m) * rs; o0.y = (hi_bf(u[0]) - m) * rs;
    o0.z = (lo_bf(u[1]) - m) * rs; o0.w = (hi_bf(u[1]) - m) * rs;
    o1.x = (lo_bf(u[2]) - m) * rs; o1.y = (hi_bf(u[2]) - m) * rs;
    o1.z = (lo_bf(u[3]) - m) * rs; o1.w = (hi_bf(u[3]) - m) * rs;
    *(float4*)&out[o]     = o0;
    *(float4*)&out[o + 4] = o1;
}

// ---------------------------------------------------------------------------
extern "C" void kernel_launch(void* const* d_in, const int* in_sizes, int n_in,
                              void* d_out, int out_size, void* d_ws, size_t ws_size,
                              hipStream_t stream)
{
    const float* x      = (const float*)d_in[0];   // (128, 32768) = (C, N)
    const float* w_qkv  = (const float*)d_in[1];
    const float* b_qkv  = (const float*)d_in[2];
    const float* rpb    = (const float*)d_in[3];
    const float* w_proj = (const float*)d_in[4];
    const float* b_proj = (const float*)d_in[5];
    const float* w_ffn1 = (const float*)d_in[6];
    const float* b_ffn1 = (const float*)d_in[7];
    const float* w_ffn2 = (const float*)d_in[8];
    const float* b_ffn2 = (const float*)d_in[9];
    float* out = (float*)d_out;

    char* ws = (char*)d_ws;
    unsigned short* qkv_bf   = (unsigned short*)(ws + 8388608);    // 25.2 MB (head-major)
    unsigned short* attnO_bf = (unsigned short*)(ws + 33554432);   // 8.39 MB
    unsigned short* x5_bf    = (unsigned short*)(ws + 41943040);   // 8.39 MB
    unsigned short* tTb      = (unsigned short*)(ws + 50331648);   // 8.39 MB bf16
    unsigned short* wproj_bf = (unsigned short*)(ws + 83984384);
    unsigned short* wffn1_bf = (unsigned short*)(ws + 84017152);
    unsigned short* wffn2_bf = (unsigned short*)(ws + 84148224);
    float*          stats    = (float*)(ws + 84279296);            // 48 KB (16+32 banks)

    // 1) qkv fused: x-transpose staging + GEMM + weight-convert + stats-zero
    qkv_fused_kernel<<<dim3(C3 / 128, NPOS / 128), 256, 0, stream>>>(
        x, w_qkv, b_qkv, w_proj, w_ffn1, w_ffn2,
        wproj_bf, wffn1_bf, wffn2_bf, stats, qkv_bf);

    // 2) tiled neighborhood attention (R12 exact)
    attn_tiled<<<dim3(1024, 8), 256, 0, stream>>>(qkv_bf, rpb, attnO_bf);

    // 3) proj + IN1 stats (16-shadow atomics)
    proj_stats_kernel<<<NPOS / 64, 256, 0, stream>>>(
        attnO_bf, wproj_bf, b_proj, x5_bf, stats);

    // 4) IN1-normalize + FFN + residual + IN2 stats (32-shadow) + transpose,
    //    32 rows/block -> 4 blocks/CU (2x occupancy)
    ffn_fused_kernel<<<NPOS / 32, 256, 0, stream>>>(
        x5_bf, wffn1_bf, b_ffn1, wffn2_bf, b_ffn2, stats, tTb);

    // 5) IN2 elementwise normalize (bf16 in, fp32 out)
    norm2_apply_kernel<<<(NPOS * CCH / 8) / 256, 256, 0, stream>>>(tTb, stats, out);
}

// Round 17
// 174.467 us; speedup vs baseline: 1.0980x; 1.0980x over previous
//
#include <hip/hip_runtime.h>
#include <hip/hip_bf16.h>
#include <math.h>

#define NPOS 32768      // 32*32*32
#define CCH  128
#define C3   384
#define CF   512
#define NSH  16         // stats shadow copies

typedef __attribute__((ext_vector_type(8))) short short8;
typedef __attribute__((ext_vector_type(4))) float f32x4;

__device__ inline float bf2f(unsigned short u) {
    union { unsigned int i; float f; } x; x.i = ((unsigned int)u) << 16; return x.f;
}
__device__ inline unsigned short f2bf(float f) {
    union { float f; unsigned int i; } x; x.f = f;
    unsigned int r = x.i + 0x7FFFu + ((x.i >> 16) & 1u);   // round-nearest-even
    return (unsigned short)(r >> 16);
}
__device__ inline float lo_bf(unsigned int u) {
    union { unsigned int i; float f; } x; x.i = u << 16; return x.f;
}
__device__ inline float hi_bf(unsigned int u) {
    union { unsigned int i; float f; } x; x.i = u & 0xffff0000u; return x.f;
}

// ---------------------------------------------------------------------------
// qkv FUSED kernel (R12 exact): x (C,N) fp32 transposed during staging,
// wqkv converted inline, head-major bf16 out; col-block-0 does side work.
// ---------------------------------------------------------------------------
__global__ __launch_bounds__(256) void qkv_fused_kernel(
    const float* __restrict__ x,        // (128, 32768) fp32
    const float* __restrict__ wqkv,     // (384, 128) fp32
    const float* __restrict__ b_qkv,
    const float* __restrict__ wp,  const float* __restrict__ w1f,
    const float* __restrict__ w2f,
    unsigned short* __restrict__ wp_b, unsigned short* __restrict__ w1_b,
    unsigned short* __restrict__ w2_b,
    float* __restrict__ stats,
    unsigned short* __restrict__ outh)  // (24, N, 16) bf16 head-major
{
    __shared__ alignas(16) unsigned short As[128 * 136];   // [n][c] bf16
    __shared__ alignas(16) unsigned short Bs[128 * 136];   // [col][c] bf16

    const int tid  = threadIdx.x;
    const int lane = tid & 63;
    const int wave = tid >> 6;
    const int wm = wave & 1, wn = wave >> 1;
    const int row0 = blockIdx.y * 128;
    const int col0 = blockIdx.x * 128;

    if (blockIdx.x == 0) {
        if (blockIdx.y < 16) {
            stats[blockIdx.y * 512 + tid] = 0.f;
            stats[blockIdx.y * 512 + 256 + tid] = 0.f;
        }
        if (tid < 144) {
            const int ci = blockIdx.y * 144 + tid;   // 0..36863 float4s
            const float* src; unsigned short* dst; int off;
            if (ci < 4096)       { src = wp;  dst = wp_b; off = ci; }
            else if (ci < 20480) { src = w1f; dst = w1_b; off = ci - 4096; }
            else                 { src = w2f; dst = w2_b; off = ci - 20480; }
            const float4 v = ((const float4*)src)[off];
            ushort4 o;
            o.x = f2bf(v.x); o.y = f2bf(v.y); o.z = f2bf(v.z); o.w = f2bf(v.w);
            ((ushort4*)dst)[off] = o;
        }
    }

    #pragma unroll
    for (int it = 0; it < 16; ++it) {
        const int idx = tid + it * 256;
        const int c  = idx >> 5;
        const int nq = idx & 31;
        const float4 v = *(const float4*)&x[(size_t)c * NPOS + row0 + nq * 4];
        As[(nq * 4 + 0) * 136 + c] = f2bf(v.x);
        As[(nq * 4 + 1) * 136 + c] = f2bf(v.y);
        As[(nq * 4 + 2) * 136 + c] = f2bf(v.z);
        As[(nq * 4 + 3) * 136 + c] = f2bf(v.w);
    }
    #pragma unroll
    for (int it = 0; it < 16; ++it) {
        const int idx = tid + it * 256;
        const int col = idx >> 5;
        const int cq  = idx & 31;
        const float4 v = *(const float4*)&wqkv[(size_t)(col0 + col) * CCH + cq * 4];
        ushort4 o;
        o.x = f2bf(v.x); o.y = f2bf(v.y); o.z = f2bf(v.z); o.w = f2bf(v.w);
        *(ushort4*)&Bs[col * 136 + cq * 4] = o;
    }
    __syncthreads();

    const f32x4 fzero = {0.f, 0.f, 0.f, 0.f};
    f32x4 acc[4][4];
    #pragma unroll
    for (int i = 0; i < 4; ++i)
        #pragma unroll
        for (int j = 0; j < 4; ++j) acc[i][j] = fzero;

    const int lr = lane & 15;
    const int lk = (lane >> 4) * 8;

    #pragma unroll
    for (int ks = 0; ks < 4; ++ks) {
        short8 af[4], bfr[4];
        #pragma unroll
        for (int i = 0; i < 4; ++i)
            af[i]  = *(const short8*)&As[(wm * 64 + i * 16 + lr) * 136 + ks * 32 + lk];
        #pragma unroll
        for (int j = 0; j < 4; ++j)
            bfr[j] = *(const short8*)&Bs[(wn * 64 + j * 16 + lr) * 136 + ks * 32 + lk];
        #pragma unroll
        for (int i = 0; i < 4; ++i)
            #pragma unroll
            for (int j = 0; j < 4; ++j)
                acc[i][j] = __builtin_amdgcn_mfma_f32_16x16x32_bf16(
                                af[i], bfr[j], acc[i][j], 0, 0, 0);
    }

    const int gr0 = row0 + wm * 64 + (lane >> 4) * 4;
    const int gc0 = col0 + wn * 64 + lr;
    #pragma unroll
    for (int j = 0; j < 4; ++j) {
        const int gc  = gc0 + j * 16;
        const int sel = gc >> 4;
        const int ch  = gc & 15;
        const float bv = b_qkv[gc];
        #pragma unroll
        for (int i = 0; i < 4; ++i) {
            #pragma unroll
            for (int r = 0; r < 4; ++r) {
                const int gr = gr0 + i * 16 + r;
                outh[((size_t)sel * NPOS + gr) * 16 + ch] = f2bf(acc[i][j][r] + bv);
            }
        }
    }
}

// ---------------------------------------------------------------------------
// Tiled neighborhood attention (R12 exact)
// ---------------------------------------------------------------------------
__global__ __launch_bounds__(256) void attn_tiled(
    const unsigned short* __restrict__ qkv,   // (24, N, 16) bf16 head-major
    const float* __restrict__ rpb,
    unsigned short* __restrict__ out)
{
    __shared__ unsigned int ksu[288 * 8];
    __shared__ unsigned int vsu[288 * 8];
    __shared__ unsigned int qsu[32 * 8];
    __shared__ float logits[32 * 29];
    __shared__ float rpbs[125];
    __shared__ float sinv[32];

    const int t  = threadIdx.x;
    const int line = ((blockIdx.x & 7) << 7) + (blockIdx.x >> 3);
    const int h  = blockIdx.y;
    const int w0 = line & 31, h0 = line >> 5;
    const int n0 = (h0 << 10) + (w0 << 5);
    const int sh0 = min(max(h0 - 1, 0), 29);
    const int sw0 = min(max(w0 - 1, 0), 29);
    const int rh_off = sh0 - h0 + 2;
    const int rw_off = sw0 - w0 + 2;

    if (t < 64) {
        const int pos = t >> 1, part = t & 1;
        const uint4 raw = *(const uint4*)&qkv[((size_t)h * NPOS + n0 + pos) * 16 + part * 8];
        *(uint4*)&qsu[pos * 8 + part * 4] = raw;
    } else if (t < 192) {
        const int i = t - 64;
        if (i < 125) rpbs[i] = rpb[h * 125 + i];
    }
    for (int c = t; c < 1152; c += 256) {
        const int p = c >> 2, part = c & 3;
        const int ihw = p >> 5, z = p & 31;
        const int ih = (ihw * 11) >> 5;
        const int iw = ihw - 3 * ih;
        const int n = ((sh0 + ih) << 10) + ((sw0 + iw) << 5) + z;
        const int kv = part >> 1;              // 0 = K, 1 = V
        const uint4 raw = *(const uint4*)&qkv[((size_t)(8 + kv * 8 + h) * NPOS + n) * 16
                                              + (part & 1) * 8];
        unsigned int* d = ((kv == 0) ? ksu : vsu) + p * 8 + (part & 1) * 4;
        *(uint4*)d = raw;
    }
    __syncthreads();

    {
        const int q = t >> 3, j = t & 7;
        const int sz = min(max(q - 1, 0), 29);
        const int rz_off = sz - q + 2;
        float qf[16];
        #pragma unroll
        for (int d2 = 0; d2 < 8; ++d2) {
            const unsigned int u = qsu[q * 8 + d2];
            qf[2 * d2] = lo_bf(u); qf[2 * d2 + 1] = hi_bf(u);
        }
        float lv[4];
        int nkk = 0;
        for (int kk = j; kk < 27; kk += 8) {
            const int ihw = kk / 3, dz = kk - 3 * ihw;
            const int ih = ihw / 3,  iw = ihw - 3 * ih;
            const int p = ihw * 32 + sz + dz;
            float a = 0.f;
            #pragma unroll
            for (int d2 = 0; d2 < 8; ++d2) {
                const unsigned int u = ksu[p * 8 + d2];
                a += qf[2 * d2] * lo_bf(u) + qf[2 * d2 + 1] * hi_bf(u);
            }
            const int bidx = ((ih + rh_off) * 5 + (iw + rw_off)) * 5 + (dz + rz_off);
            lv[nkk++] = a * 0.25f + rpbs[bidx];
        }
        float mx = -1e30f;
        #pragma unroll
        for (int u = 0; u < 4; ++u) if (u < nkk) mx = fmaxf(mx, lv[u]);
        mx = fmaxf(mx, __shfl_xor(mx, 1));
        mx = fmaxf(mx, __shfl_xor(mx, 2));
        mx = fmaxf(mx, __shfl_xor(mx, 4));
        float s = 0.f;
        int u = 0;
        for (int kk = j; kk < 27; kk += 8) {
            const float e = __expf(lv[u++] - mx);
            logits[q * 29 + kk] = e;
            s += e;
        }
        s += __shfl_xor(s, 1);
        s += __shfl_xor(s, 2);
        s += __shfl_xor(s, 4);
        if (j == 0) sinv[q] = 1.f / s;
    }
    __syncthreads();

    {
        const int q = t >> 3, d2 = t & 7;
        const int sz = min(max(q - 1, 0), 29);
        float ax = 0.f, ay = 0.f;
        #pragma unroll
        for (int kk = 0; kk < 27; ++kk) {
            const int p = (kk / 3) * 32 + sz + (kk % 3);
            const float w = logits[q * 29 + kk];
            const unsigned int u = vsu[p * 8 + d2];
            ax += w * lo_bf(u); ay += w * hi_bf(u);
        }
        const float inv = sinv[q];
        const unsigned int o = ((unsigned int)f2bf(ay * inv) << 16)
                             |  (unsigned int)f2bf(ax * inv);
        *(unsigned int*)&out[(size_t)(n0 + q) * CCH + h * 16 + d2 * 2] = o;
    }
}

// ---------------------------------------------------------------------------
// K1: proj GEMM (K=128) + bias -> x5 (bf16) + IN1 stats (16-shadow banks)
// (R12 exact)
// ---------------------------------------------------------------------------
__global__ __launch_bounds__(256) void proj_stats_kernel(
    const unsigned short* __restrict__ attnO,   // (N,128) bf16
    const unsigned short* __restrict__ wproj,   // (128,128) bf16
    const float* __restrict__ b_proj,
    unsigned short* __restrict__ x5b,           // (N,128) bf16 out
    float* __restrict__ stats)                  // [s*256 + {c,128+c}], s<16 : IN1
{
    __shared__ float red[256];

    const int t    = threadIdx.x;
    const int lane = t & 63;
    const int wn   = t >> 6;
    const int lr = lane & 15;
    const int lg = lane >> 4;
    const int lk = lg * 8;
    const int n0 = blockIdx.x * 64;
    const int sh = (blockIdx.x & (NSH - 1)) * 256;

    red[t] = 0.f;

    short8 wf[2][4];
    #pragma unroll
    for (int j = 0; j < 2; ++j)
        #pragma unroll
        for (int ks = 0; ks < 4; ++ks)
            wf[j][ks] = *(const short8*)&wproj[(wn * 32 + j * 16 + lr) * CCH + ks * 32 + lk];

    const f32x4 fzero = {0.f, 0.f, 0.f, 0.f};
    f32x4 acc[4][2];
    #pragma unroll
    for (int i = 0; i < 4; ++i)
        #pragma unroll
        for (int j = 0; j < 2; ++j) acc[i][j] = fzero;

    #pragma unroll
    for (int ks = 0; ks < 4; ++ks) {
        short8 af[4];
        #pragma unroll
        for (int i = 0; i < 4; ++i)
            af[i] = *(const short8*)&attnO[(size_t)(n0 + i * 16 + lr) * CCH + ks * 32 + lk];
        #pragma unroll
        for (int i = 0; i < 4; ++i)
            #pragma unroll
            for (int j = 0; j < 2; ++j)
                acc[i][j] = __builtin_amdgcn_mfma_f32_16x16x32_bf16(
                                af[i], wf[j][ks], acc[i][j], 0, 0, 0);
    }
    __syncthreads();   // red[] zeroed before atomics

    #pragma unroll
    for (int j = 0; j < 2; ++j) {
        const int gc = wn * 32 + j * 16 + lr;
        const float bv = b_proj[gc];
        float s = 0.f, q = 0.f;
        #pragma unroll
        for (int i = 0; i < 4; ++i)
            #pragma unroll
            for (int r = 0; r < 4; ++r) {
                const int gr = i * 16 + lg * 4 + r;
                const float v = acc[i][j][r] + bv;
                s += v; q += v * v;
                x5b[(size_t)(n0 + gr) * CCH + gc] = f2bf(v);
            }
        atomicAdd(&red[gc], s);
        atomicAdd(&red[128 + gc], q);
    }
    __syncthreads();
    if (t < 128) {
        atomicAdd(&stats[sh + t],       red[t]);
        atomicAdd(&stats[sh + 128 + t], red[128 + t]);
    }
}

// ---------------------------------------------------------------------------
// K2: IN1-normalize -> FFN (4 chunks, PER-BLOCK ROTATED ORDER) -> +residual
//     -> IN2 stats (16-shadow) -> transpose -> tTb (C,N) bf16. (R12 base)
// Chunk rotation: concurrent blocks read DIFFERENT weight chunks, breaking
// the all-blocks-same-line L2 request storm (the suspected uncounted stall).
// ---------------------------------------------------------------------------
__global__ __launch_bounds__(256) void ffn_fused_kernel(
    const unsigned short* __restrict__ x5b,     // (N,128) bf16
    const unsigned short* __restrict__ w1,      // (512,128) bf16
    const float* __restrict__ b1,
    const unsigned short* __restrict__ w2,      // (128,512) bf16
    const float* __restrict__ b2,
    float* __restrict__ stats,                  // [0:4096) IN1 shadows, [4096:8192) IN2
    unsigned short* __restrict__ tTb)           // (128, 32768) bf16 out
{
    __shared__ alignas(16) unsigned short pool[2 * 8704];   // As | Hs
    unsigned short* As = pool;
    unsigned short* Hs = pool + 8704;
    __shared__ float red[256];
    __shared__ float ms[128];
    __shared__ float rss[128];

    const int t    = threadIdx.x;
    const int lane = t & 63;
    const int wn   = t >> 6;
    const int lr = lane & 15;
    const int lg = lane >> 4;
    const int lk = lg * 8;
    const int n0 = blockIdx.x * 64;
    const int sh = (blockIdx.x & (NSH - 1)) * 256;
    const int crot = blockIdx.x & 3;             // per-block chunk rotation
    const float invN = 1.f / (float)NPOS;
    const f32x4 fzero = {0.f, 0.f, 0.f, 0.f};

    red[t] = 0.f;
    if (t < 128) {
        float s0 = 0.f, s1 = 0.f;
        #pragma unroll
        for (int s = 0; s < NSH; ++s) {
            s0 += stats[s * 256 + t];
            s1 += stats[s * 256 + 128 + t];
        }
        const float m = s0 * invN;
        const float v = s1 * invN - m * m;
        ms[t]  = m;
        rss[t] = rsqrtf(v + 1e-5f);
    }
    uint4 px[4];
    #pragma unroll
    for (int it = 0; it < 4; ++it) {
        const int idx = t + it * 256;
        const int row = idx >> 4, c0 = (idx & 15) * 8;
        px[it] = *(const uint4*)&x5b[(size_t)(n0 + row) * CCH + c0];
    }
    __syncthreads();

    #pragma unroll
    for (int it = 0; it < 4; ++it) {
        const int idx = t + it * 256;
        const int row = idx >> 4, c0 = (idx & 15) * 8;
        unsigned int u[4] = {px[it].x, px[it].y, px[it].z, px[it].w};
        #pragma unroll
        for (int p = 0; p < 4; ++p) {
            const int c = c0 + 2 * p;
            const float a = (lo_bf(u[p]) - ms[c])     * rss[c];
            const float b = (hi_bf(u[p]) - ms[c + 1]) * rss[c + 1];
            u[p] = ((unsigned int)f2bf(b) << 16) | (unsigned int)f2bf(a);
        }
        uint4 w; w.x = u[0]; w.y = u[1]; w.z = u[2]; w.w = u[3];
        *(uint4*)&As[row * 136 + c0] = w;
    }
    __syncthreads();

    f32x4 acc[4][2];
    #pragma unroll
    for (int i = 0; i < 4; ++i)
        #pragma unroll
        for (int j = 0; j < 2; ++j) acc[i][j] = fzero;

    #pragma unroll 1
    for (int cc = 0; cc < 4; ++cc) {
        const int ccp = (cc + crot) & 3;         // rotated chunk index

        short8 w1f[2][4];
        #pragma unroll
        for (int j = 0; j < 2; ++j)
            #pragma unroll
            for (int ks = 0; ks < 4; ++ks)
                w1f[j][ks] = *(const short8*)&w1[
                    (size_t)(ccp * 128 + wn * 32 + j * 16 + lr) * CCH + ks * 32 + lk];

        f32x4 hacc[4][2];
        #pragma unroll
        for (int i = 0; i < 4; ++i)
            #pragma unroll
            for (int j = 0; j < 2; ++j) hacc[i][j] = fzero;
        #pragma unroll
        for (int ks = 0; ks < 4; ++ks) {
            short8 af[4];
            #pragma unroll
            for (int i = 0; i < 4; ++i)
                af[i] = *(const short8*)&As[(i * 16 + lr) * 136 + ks * 32 + lk];
            #pragma unroll
            for (int i = 0; i < 4; ++i)
                #pragma unroll
                for (int j = 0; j < 2; ++j)
                    hacc[i][j] = __builtin_amdgcn_mfma_f32_16x16x32_bf16(
                                    af[i], w1f[j][ks], hacc[i][j], 0, 0, 0);
        }

        short8 w2f[2][4];
        #pragma unroll
        for (int j = 0; j < 2; ++j)
            #pragma unroll
            for (int ks = 0; ks < 4; ++ks)
                w2f[j][ks] = *(const short8*)&w2[
                    (size_t)(wn * 32 + j * 16 + lr) * CF + ccp * 128 + ks * 32 + lk];

        #pragma unroll
        for (int j = 0; j < 2; ++j) {
            const int gc = wn * 32 + j * 16 + lr;
            const float bv = b1[ccp * 128 + gc];
            #pragma unroll
            for (int i = 0; i < 4; ++i)
                #pragma unroll
                for (int r = 0; r < 4; ++r) {
                    float v = hacc[i][j][r] + bv;
                    const float g = 0.7978845608028654f * (v + 0.044715f * v * v * v);
                    const float e = __expf(2.f * g);
                    v = v * (e / (e + 1.f));
                    Hs[(i * 16 + lg * 4 + r) * 136 + gc] = f2bf(v);
                }
        }
        __syncthreads();   // Hs ready

        #pragma unroll
        for (int ks = 0; ks < 4; ++ks) {
            short8 af[4];
            #pragma unroll
            for (int i = 0; i < 4; ++i)
                af[i] = *(const short8*)&Hs[(i * 16 + lr) * 136 + ks * 32 + lk];
            #pragma unroll
            for (int i = 0; i < 4; ++i)
                #pragma unroll
                for (int j = 0; j < 2; ++j)
                    acc[i][j] = __builtin_amdgcn_mfma_f32_16x16x32_bf16(
                                    af[i], w2f[j][ks], acc[i][j], 0, 0, 0);
        }
        __syncthreads();   // Hs consumed
    }

    #pragma unroll
    for (int j = 0; j < 2; ++j) {
        const int gc = wn * 32 + j * 16 + lr;
        const float bv = b2[gc];
        float s = 0.f, q = 0.f;
        #pragma unroll
        for (int i = 0; i < 4; ++i)
            #pragma unroll
            for (int r = 0; r < 4; ++r) {
                const int gr = i * 16 + lg * 4 + r;
                const float v = acc[i][j][r] + bv + bf2f(As[gr * 136 + gc]);
                acc[i][j][r] = v;
                s += v; q += v * v;
            }
        atomicAdd(&red[gc], s);
        atomicAdd(&red[128 + gc], q);
    }
    __syncthreads();
    if (t < 128) {
        atomicAdd(&stats[4096 + sh + t],       red[t]);
        atomicAdd(&stats[4096 + sh + 128 + t], red[128 + t]);
    }

    float* tr = (float*)pool;        // 128 x 68 fp32 = 34816 B
    #pragma unroll
    for (int j = 0; j < 2; ++j) {
        const int gc = wn * 32 + j * 16 + lr;
        #pragma unroll
        for (int i = 0; i < 4; ++i)
            #pragma unroll
            for (int r = 0; r < 4; ++r) {
                const int gr = i * 16 + lg * 4 + r;
                tr[gc * 68 + gr] = acc[i][j][r];
            }
    }
    __syncthreads();
    #pragma unroll
    for (int it = 0; it < 8; ++it) {
        const int idx = t + it * 256;
        const int c = idx >> 4, ch = (idx & 15) * 4;
        ushort4 o4;
        o4.x = f2bf(tr[c * 68 + ch + 0]);
        o4.y = f2bf(tr[c * 68 + ch + 1]);
        o4.z = f2bf(tr[c * 68 + ch + 2]);
        o4.w = f2bf(tr[c * 68 + ch + 3]);
        *(ushort4*)&tTb[(size_t)c * NPOS + n0 + ch] = o4;
    }
}

// ---------------------------------------------------------------------------
// K3: IN2 elementwise normalize, bf16 (C,N) in -> fp32 (C,N) out (R12 exact)
// ---------------------------------------------------------------------------
__global__ __launch_bounds__(256) void norm2_apply_kernel(
    const unsigned short* __restrict__ tTb, const float* __restrict__ stats,
    float* __restrict__ out)
{
    const int i = blockIdx.x * 256 + threadIdx.x;
    const size_t o = (size_t)i * 8;
    const int c = (int)(o >> 15);
    const float invN = 1.f / (float)NPOS;
    float s0 = 0.f, s1 = 0.f;
    #pragma unroll
    for (int s = 0; s < NSH; ++s) {
        s0 += stats[4096 + s * 256 + c];
        s1 += stats[4096 + s * 256 + 128 + c];
    }
    const float m  = s0 * invN;
    const float vr = s1 * invN - m * m;
    const float rs = rsqrtf(vr + 1e-5f);
    const uint4 raw = *(const uint4*)&tTb[o];
    const unsigned int u[4] = {raw.x, raw.y, raw.z, raw.w};
    float4 o0, o1;
    o0.x = (lo_bf(u[0]) - m) * rs; o0.y = (hi_bf(u[0]) - m) * rs;
    o0.z = (lo_bf(u[1]) - m) * rs; o0.w = (hi_bf(u[1]) - m) * rs;
    o1.x = (lo_bf(u[2]) - m) * rs; o1.y = (hi_bf(u[2]) - m) * rs;
    o1.z = (lo_bf(u[3]) - m) * rs; o1.w = (hi_bf(u[3]) - m) * rs;
    *(float4*)&out[o]     = o0;
    *(float4*)&out[o + 4] = o1;
}

// ---------------------------------------------------------------------------
extern "C" void kernel_launch(void* const* d_in, const int* in_sizes, int n_in,
                              void* d_out, int out_size, void* d_ws, size_t ws_size,
                              hipStream_t stream)
{
    const float* x      = (const float*)d_in[0];   // (128, 32768) = (C, N)
    const float* w_qkv  = (const float*)d_in[1];
    const float* b_qkv  = (const float*)d_in[2];
    const float* rpb    = (const float*)d_in[3];
    const float* w_proj = (const float*)d_in[4];
    const float* b_proj = (const float*)d_in[5];
    const float* w_ffn1 = (const float*)d_in[6];
    const float* b_ffn1 = (const float*)d_in[7];
    const float* w_ffn2 = (const float*)d_in[8];
    const float* b_ffn2 = (const float*)d_in[9];
    float* out = (float*)d_out;

    char* ws = (char*)d_ws;
    unsigned short* qkv_bf   = (unsigned short*)(ws + 8388608);    // 25.2 MB (head-major)
    unsigned short* attnO_bf = (unsigned short*)(ws + 33554432);   // 8.39 MB
    unsigned short* x5_bf    = (unsigned short*)(ws + 41943040);   // 8.39 MB
    unsigned short* tTb      = (unsigned short*)(ws + 50331648);   // 8.39 MB bf16
    unsigned short* wproj_bf = (unsigned short*)(ws + 83984384);
    unsigned short* wffn1_bf = (unsigned short*)(ws + 84017152);
    unsigned short* wffn2_bf = (unsigned short*)(ws + 84148224);
    float*          stats    = (float*)(ws + 84279296);            // 32 KB

    // 1) qkv fused: x-transpose staging + GEMM + weight-convert + stats-zero
    qkv_fused_kernel<<<dim3(C3 / 128, NPOS / 128), 256, 0, stream>>>(
        x, w_qkv, b_qkv, w_proj, w_ffn1, w_ffn2,
        wproj_bf, wffn1_bf, wffn2_bf, stats, qkv_bf);

    // 2) tiled neighborhood attention (R12 exact)
    attn_tiled<<<dim3(1024, 8), 256, 0, stream>>>(qkv_bf, rpb, attnO_bf);

    // 3) proj + IN1 stats (16-shadow atomics)
    proj_stats_kernel<<<NPOS / 64, 256, 0, stream>>>(
        attnO_bf, wproj_bf, b_proj, x5_bf, stats);

    // 4) IN1-normalize + FFN (rotated chunk order) + residual + IN2 stats
    //    + transpose (bf16)
    ffn_fused_kernel<<<NPOS / 64, 256, 0, stream>>>(
        x5_bf, wffn1_bf, b_ffn1, wffn2_bf, b_ffn2, stats, tTb);

    // 5) IN2 elementwise normalize (bf16 in, fp32 out)
    norm2_apply_kernel<<<(NPOS * CCH / 8) / 256, 256, 0, stream>>>(tTb, stats, out);
}

// Round 18
// 172.009 us; speedup vs baseline: 1.1137x; 1.0143x over previous
//
#include <hip/hip_runtime.h>
#include <hip/hip_bf16.h>
#include <hip/hip_fp16.h>
#include <math.h>

#define NPOS 32768      // 32*32*32
#define CCH  128
#define C3   384
#define CF   512
#define NSH  16         // stats shadow copies

typedef __attribute__((ext_vector_type(8))) short short8;
typedef __attribute__((ext_vector_type(4))) float f32x4;

__device__ inline float bf2f(unsigned short u) {
    union { unsigned int i; float f; } x; x.i = ((unsigned int)u) << 16; return x.f;
}
__device__ inline unsigned short f2bf(float f) {
    union { float f; unsigned int i; } x; x.f = f;
    unsigned int r = x.i + 0x7FFFu + ((x.i >> 16) & 1u);   // round-nearest-even
    return (unsigned short)(r >> 16);
}
__device__ inline float lo_bf(unsigned int u) {
    union { unsigned int i; float f; } x; x.i = u << 16; return x.f;
}
__device__ inline float hi_bf(unsigned int u) {
    union { unsigned int i; float f; } x; x.i = u & 0xffff0000u; return x.f;
}
__device__ inline unsigned short f2h(float f) {
    __half h = __float2half(f);
    return *reinterpret_cast<unsigned short*>(&h);
}

// ---------------------------------------------------------------------------
// qkv FUSED kernel: identical to R17 except epilogue writes F16 (for packed
// __hfma2 attention math) instead of bf16.
// ---------------------------------------------------------------------------
__global__ __launch_bounds__(256) void qkv_fused_kernel(
    const float* __restrict__ x,        // (128, 32768) fp32
    const float* __restrict__ wqkv,     // (384, 128) fp32
    const float* __restrict__ b_qkv,
    const float* __restrict__ wp,  const float* __restrict__ w1f,
    const float* __restrict__ w2f,
    unsigned short* __restrict__ wp_b, unsigned short* __restrict__ w1_b,
    unsigned short* __restrict__ w2_b,
    float* __restrict__ stats,
    unsigned short* __restrict__ outh)  // (24, N, 16) F16 head-major
{
    __shared__ alignas(16) unsigned short As[128 * 136];   // [n][c] bf16
    __shared__ alignas(16) unsigned short Bs[128 * 136];   // [col][c] bf16

    const int tid  = threadIdx.x;
    const int lane = tid & 63;
    const int wave = tid >> 6;
    const int wm = wave & 1, wn = wave >> 1;
    const int row0 = blockIdx.y * 128;
    const int col0 = blockIdx.x * 128;

    if (blockIdx.x == 0) {
        if (blockIdx.y < 16) {
            stats[blockIdx.y * 512 + tid] = 0.f;
            stats[blockIdx.y * 512 + 256 + tid] = 0.f;
        }
        if (tid < 144) {
            const int ci = blockIdx.y * 144 + tid;   // 0..36863 float4s
            const float* src; unsigned short* dst; int off;
            if (ci < 4096)       { src = wp;  dst = wp_b; off = ci; }
            else if (ci < 20480) { src = w1f; dst = w1_b; off = ci - 4096; }
            else                 { src = w2f; dst = w2_b; off = ci - 20480; }
            const float4 v = ((const float4*)src)[off];
            ushort4 o;
            o.x = f2bf(v.x); o.y = f2bf(v.y); o.z = f2bf(v.z); o.w = f2bf(v.w);
            ((ushort4*)dst)[off] = o;
        }
    }

    #pragma unroll
    for (int it = 0; it < 16; ++it) {
        const int idx = tid + it * 256;
        const int c  = idx >> 5;
        const int nq = idx & 31;
        const float4 v = *(const float4*)&x[(size_t)c * NPOS + row0 + nq * 4];
        As[(nq * 4 + 0) * 136 + c] = f2bf(v.x);
        As[(nq * 4 + 1) * 136 + c] = f2bf(v.y);
        As[(nq * 4 + 2) * 136 + c] = f2bf(v.z);
        As[(nq * 4 + 3) * 136 + c] = f2bf(v.w);
    }
    #pragma unroll
    for (int it = 0; it < 16; ++it) {
        const int idx = tid + it * 256;
        const int col = idx >> 5;
        const int cq  = idx & 31;
        const float4 v = *(const float4*)&wqkv[(size_t)(col0 + col) * CCH + cq * 4];
        ushort4 o;
        o.x = f2bf(v.x); o.y = f2bf(v.y); o.z = f2bf(v.z); o.w = f2bf(v.w);
        *(ushort4*)&Bs[col * 136 + cq * 4] = o;
    }
    __syncthreads();

    const f32x4 fzero = {0.f, 0.f, 0.f, 0.f};
    f32x4 acc[4][4];
    #pragma unroll
    for (int i = 0; i < 4; ++i)
        #pragma unroll
        for (int j = 0; j < 4; ++j) acc[i][j] = fzero;

    const int lr = lane & 15;
    const int lk = (lane >> 4) * 8;

    #pragma unroll
    for (int ks = 0; ks < 4; ++ks) {
        short8 af[4], bfr[4];
        #pragma unroll
        for (int i = 0; i < 4; ++i)
            af[i]  = *(const short8*)&As[(wm * 64 + i * 16 + lr) * 136 + ks * 32 + lk];
        #pragma unroll
        for (int j = 0; j < 4; ++j)
            bfr[j] = *(const short8*)&Bs[(wn * 64 + j * 16 + lr) * 136 + ks * 32 + lk];
        #pragma unroll
        for (int i = 0; i < 4; ++i)
            #pragma unroll
            for (int j = 0; j < 4; ++j)
                acc[i][j] = __builtin_amdgcn_mfma_f32_16x16x32_bf16(
                                af[i], bfr[j], acc[i][j], 0, 0, 0);
    }

    const int gr0 = row0 + wm * 64 + (lane >> 4) * 4;
    const int gc0 = col0 + wn * 64 + lr;
    #pragma unroll
    for (int j = 0; j < 4; ++j) {
        const int gc  = gc0 + j * 16;
        const int sel = gc >> 4;
        const int ch  = gc & 15;
        const float bv = b_qkv[gc];
        #pragma unroll
        for (int i = 0; i < 4; ++i) {
            #pragma unroll
            for (int r = 0; r < 4; ++r) {
                const int gr = gr0 + i * 16 + r;
                outh[((size_t)sel * NPOS + gr) * 16 + ch] = f2h(acc[i][j][r] + bv);
            }
        }
    }
}

// ---------------------------------------------------------------------------
// Tiled neighborhood attention: F16 qkv input; QK & PV inner loops use
// packed __hfma2 (v_pk_fma_f16) — no per-element unpack, half the VALU ops.
// Structure otherwise R12-exact (line blocks, wave-parallel softmax).
// ---------------------------------------------------------------------------
__global__ __launch_bounds__(256) void attn_tiled(
    const unsigned short* __restrict__ qkv,   // (24, N, 16) f16 head-major
    const float* __restrict__ rpb,
    unsigned short* __restrict__ out)         // (N,128) bf16
{
    __shared__ unsigned int ksu[288 * 8];
    __shared__ unsigned int vsu[288 * 8];
    __shared__ unsigned int qsu[32 * 8];
    __shared__ float logits[32 * 29];
    __shared__ float rpbs[125];
    __shared__ float sinv[32];

    const int t  = threadIdx.x;
    const int line = ((blockIdx.x & 7) << 7) + (blockIdx.x >> 3);
    const int h  = blockIdx.y;
    const int w0 = line & 31, h0 = line >> 5;
    const int n0 = (h0 << 10) + (w0 << 5);
    const int sh0 = min(max(h0 - 1, 0), 29);
    const int sw0 = min(max(w0 - 1, 0), 29);
    const int rh_off = sh0 - h0 + 2;
    const int rw_off = sw0 - w0 + 2;

    if (t < 64) {
        const int pos = t >> 1, part = t & 1;
        const uint4 raw = *(const uint4*)&qkv[((size_t)h * NPOS + n0 + pos) * 16 + part * 8];
        *(uint4*)&qsu[pos * 8 + part * 4] = raw;
    } else if (t < 192) {
        const int i = t - 64;
        if (i < 125) rpbs[i] = rpb[h * 125 + i];
    }
    for (int c = t; c < 1152; c += 256) {
        const int p = c >> 2, part = c & 3;
        const int ihw = p >> 5, z = p & 31;
        const int ih = (ihw * 11) >> 5;
        const int iw = ihw - 3 * ih;
        const int n = ((sh0 + ih) << 10) + ((sw0 + iw) << 5) + z;
        const int kv = part >> 1;              // 0 = K, 1 = V
        const uint4 raw = *(const uint4*)&qkv[((size_t)(8 + kv * 8 + h) * NPOS + n) * 16
                                              + (part & 1) * 8];
        unsigned int* d = ((kv == 0) ? ksu : vsu) + p * 8 + (part & 1) * 4;
        *(uint4*)d = raw;
    }
    __syncthreads();

    // ---- QK^T (packed f16) + wave-parallel softmax : thread = (query, j)
    {
        const int q = t >> 3, j = t & 7;
        const int sz = min(max(q - 1, 0), 29);
        const int rz_off = sz - q + 2;
        __half2 qh[8];
        #pragma unroll
        for (int d2 = 0; d2 < 8; ++d2)
            qh[d2] = *(const __half2*)&qsu[q * 8 + d2];
        float lv[4];
        int nkk = 0;
        for (int kk = j; kk < 27; kk += 8) {
            const int ihw = kk / 3, dz = kk - 3 * ihw;
            const int ih = ihw / 3,  iw = ihw - 3 * ih;
            const int p = ihw * 32 + sz + dz;
            __half2 acc2 = __float2half2_rn(0.f);
            #pragma unroll
            for (int d2 = 0; d2 < 8; ++d2)
                acc2 = __hfma2(qh[d2], *(const __half2*)&ksu[p * 8 + d2], acc2);
            const float2 f2 = __half22float2(acc2);
            const float a = f2.x + f2.y;
            const int bidx = ((ih + rh_off) * 5 + (iw + rw_off)) * 5 + (dz + rz_off);
            lv[nkk++] = a * 0.25f + rpbs[bidx];
        }
        float mx = -1e30f;
        #pragma unroll
        for (int u = 0; u < 4; ++u) if (u < nkk) mx = fmaxf(mx, lv[u]);
        mx = fmaxf(mx, __shfl_xor(mx, 1));
        mx = fmaxf(mx, __shfl_xor(mx, 2));
        mx = fmaxf(mx, __shfl_xor(mx, 4));
        float s = 0.f;
        int u = 0;
        for (int kk = j; kk < 27; kk += 8) {
            const float e = __expf(lv[u++] - mx);
            logits[q * 29 + kk] = e;
            s += e;
        }
        s += __shfl_xor(s, 1);
        s += __shfl_xor(s, 2);
        s += __shfl_xor(s, 4);
        if (j == 0) sinv[q] = 1.f / s;
    }
    __syncthreads();

    // ---- PV (packed f16): thread = (query, dim-pair)
    {
        const int q = t >> 3, d2 = t & 7;
        const int sz = min(max(q - 1, 0), 29);
        __half2 acc2 = __float2half2_rn(0.f);
        #pragma unroll
        for (int kk = 0; kk < 27; ++kk) {
            const int p = (kk / 3) * 32 + sz + (kk % 3);
            const __half2 w2 = __float2half2_rn(logits[q * 29 + kk]);
            acc2 = __hfma2(w2, *(const __half2*)&vsu[p * 8 + d2], acc2);
        }
        const float2 f2 = __half22float2(acc2);
        const float inv = sinv[q];
        const unsigned int o = ((unsigned int)f2bf(f2.y * inv) << 16)
                             |  (unsigned int)f2bf(f2.x * inv);
        *(unsigned int*)&out[(size_t)(n0 + q) * CCH + h * 16 + d2 * 2] = o;
    }
}

// ---------------------------------------------------------------------------
// K1: proj GEMM (K=128) + bias -> x5 (bf16) + IN1 stats (16-shadow banks)
// (R17 exact)
// ---------------------------------------------------------------------------
__global__ __launch_bounds__(256) void proj_stats_kernel(
    const unsigned short* __restrict__ attnO,   // (N,128) bf16
    const unsigned short* __restrict__ wproj,   // (128,128) bf16
    const float* __restrict__ b_proj,
    unsigned short* __restrict__ x5b,           // (N,128) bf16 out
    float* __restrict__ stats)                  // [s*256 + {c,128+c}], s<16 : IN1
{
    __shared__ float red[256];

    const int t    = threadIdx.x;
    const int lane = t & 63;
    const int wn   = t >> 6;
    const int lr = lane & 15;
    const int lg = lane >> 4;
    const int lk = lg * 8;
    const int n0 = blockIdx.x * 64;
    const int sh = (blockIdx.x & (NSH - 1)) * 256;

    red[t] = 0.f;

    short8 wf[2][4];
    #pragma unroll
    for (int j = 0; j < 2; ++j)
        #pragma unroll
        for (int ks = 0; ks < 4; ++ks)
            wf[j][ks] = *(const short8*)&wproj[(wn * 32 + j * 16 + lr) * CCH + ks * 32 + lk];

    const f32x4 fzero = {0.f, 0.f, 0.f, 0.f};
    f32x4 acc[4][2];
    #pragma unroll
    for (int i = 0; i < 4; ++i)
        #pragma unroll
        for (int j = 0; j < 2; ++j) acc[i][j] = fzero;

    #pragma unroll
    for (int ks = 0; ks < 4; ++ks) {
        short8 af[4];
        #pragma unroll
        for (int i = 0; i < 4; ++i)
            af[i] = *(const short8*)&attnO[(size_t)(n0 + i * 16 + lr) * CCH + ks * 32 + lk];
        #pragma unroll
        for (int i = 0; i < 4; ++i)
            #pragma unroll
            for (int j = 0; j < 2; ++j)
                acc[i][j] = __builtin_amdgcn_mfma_f32_16x16x32_bf16(
                                af[i], wf[j][ks], acc[i][j], 0, 0, 0);
    }
    __syncthreads();   // red[] zeroed before atomics

    #pragma unroll
    for (int j = 0; j < 2; ++j) {
        const int gc = wn * 32 + j * 16 + lr;
        const float bv = b_proj[gc];
        float s = 0.f, q = 0.f;
        #pragma unroll
        for (int i = 0; i < 4; ++i)
            #pragma unroll
            for (int r = 0; r < 4; ++r) {
                const int gr = i * 16 + lg * 4 + r;
                const float v = acc[i][j][r] + bv;
                s += v; q += v * v;
                x5b[(size_t)(n0 + gr) * CCH + gc] = f2bf(v);
            }
        atomicAdd(&red[gc], s);
        atomicAdd(&red[128 + gc], q);
    }
    __syncthreads();
    if (t < 128) {
        atomicAdd(&stats[sh + t],       red[t]);
        atomicAdd(&stats[sh + 128 + t], red[128 + t]);
    }
}

// ---------------------------------------------------------------------------
// K2: IN1-normalize -> FFN (4 chunks, per-block ROTATED order) -> +residual
//     -> IN2 stats (16-shadow) -> transpose -> tTb (C,N) bf16. (R17 exact)
// ---------------------------------------------------------------------------
__global__ __launch_bounds__(256) void ffn_fused_kernel(
    const unsigned short* __restrict__ x5b,     // (N,128) bf16
    const unsigned short* __restrict__ w1,      // (512,128) bf16
    const float* __restrict__ b1,
    const unsigned short* __restrict__ w2,      // (128,512) bf16
    const float* __restrict__ b2,
    float* __restrict__ stats,                  // [0:4096) IN1 shadows, [4096:8192) IN2
    unsigned short* __restrict__ tTb)           // (128, 32768) bf16 out
{
    __shared__ alignas(16) unsigned short pool[2 * 8704];   // As | Hs
    unsigned short* As = pool;
    unsigned short* Hs = pool + 8704;
    __shared__ float red[256];
    __shared__ float ms[128];
    __shared__ float rss[128];

    const int t    = threadIdx.x;
    const int lane = t & 63;
    const int wn   = t >> 6;
    const int lr = lane & 15;
    const int lg = lane >> 4;
    const int lk = lg * 8;
    const int n0 = blockIdx.x * 64;
    const int sh = (blockIdx.x & (NSH - 1)) * 256;
    const int crot = blockIdx.x & 3;             // per-block chunk rotation
    const float invN = 1.f / (float)NPOS;
    const f32x4 fzero = {0.f, 0.f, 0.f, 0.f};

    red[t] = 0.f;
    if (t < 128) {
        float s0 = 0.f, s1 = 0.f;
        #pragma unroll
        for (int s = 0; s < NSH; ++s) {
            s0 += stats[s * 256 + t];
            s1 += stats[s * 256 + 128 + t];
        }
        const float m = s0 * invN;
        const float v = s1 * invN - m * m;
        ms[t]  = m;
        rss[t] = rsqrtf(v + 1e-5f);
    }
    uint4 px[4];
    #pragma unroll
    for (int it = 0; it < 4; ++it) {
        const int idx = t + it * 256;
        const int row = idx >> 4, c0 = (idx & 15) * 8;
        px[it] = *(const uint4*)&x5b[(size_t)(n0 + row) * CCH + c0];
    }
    __syncthreads();

    #pragma unroll
    for (int it = 0; it < 4; ++it) {
        const int idx = t + it * 256;
        const int row = idx >> 4, c0 = (idx & 15) * 8;
        unsigned int u[4] = {px[it].x, px[it].y, px[it].z, px[it].w};
        #pragma unroll
        for (int p = 0; p < 4; ++p) {
            const int c = c0 + 2 * p;
            const float a = (lo_bf(u[p]) - ms[c])     * rss[c];
            const float b = (hi_bf(u[p]) - ms[c + 1]) * rss[c + 1];
            u[p] = ((unsigned int)f2bf(b) << 16) | (unsigned int)f2bf(a);
        }
        uint4 w; w.x = u[0]; w.y = u[1]; w.z = u[2]; w.w = u[3];
        *(uint4*)&As[row * 136 + c0] = w;
    }
    __syncthreads();

    f32x4 acc[4][2];
    #pragma unroll
    for (int i = 0; i < 4; ++i)
        #pragma unroll
        for (int j = 0; j < 2; ++j) acc[i][j] = fzero;

    #pragma unroll 1
    for (int cc = 0; cc < 4; ++cc) {
        const int ccp = (cc + crot) & 3;         // rotated chunk index

        short8 w1f[2][4];
        #pragma unroll
        for (int j = 0; j < 2; ++j)
            #pragma unroll
            for (int ks = 0; ks < 4; ++ks)
                w1f[j][ks] = *(const short8*)&w1[
                    (size_t)(ccp * 128 + wn * 32 + j * 16 + lr) * CCH + ks * 32 + lk];

        f32x4 hacc[4][2];
        #pragma unroll
        for (int i = 0; i < 4; ++i)
            #pragma unroll
            for (int j = 0; j < 2; ++j) hacc[i][j] = fzero;
        #pragma unroll
        for (int ks = 0; ks < 4; ++ks) {
            short8 af[4];
            #pragma unroll
            for (int i = 0; i < 4; ++i)
                af[i] = *(const short8*)&As[(i * 16 + lr) * 136 + ks * 32 + lk];
            #pragma unroll
            for (int i = 0; i < 4; ++i)
                #pragma unroll
                for (int j = 0; j < 2; ++j)
                    hacc[i][j] = __builtin_amdgcn_mfma_f32_16x16x32_bf16(
                                    af[i], w1f[j][ks], hacc[i][j], 0, 0, 0);
        }

        short8 w2f[2][4];
        #pragma unroll
        for (int j = 0; j < 2; ++j)
            #pragma unroll
            for (int ks = 0; ks < 4; ++ks)
                w2f[j][ks] = *(const short8*)&w2[
                    (size_t)(wn * 32 + j * 16 + lr) * CF + ccp * 128 + ks * 32 + lk];

        #pragma unroll
        for (int j = 0; j < 2; ++j) {
            const int gc = wn * 32 + j * 16 + lr;
            const float bv = b1[ccp * 128 + gc];
            #pragma unroll
            for (int i = 0; i < 4; ++i)
                #pragma unroll
                for (int r = 0; r < 4; ++r) {
                    float v = hacc[i][j][r] + bv;
                    const float g = 0.7978845608028654f * (v + 0.044715f * v * v * v);
                    const float e = __expf(2.f * g);
                    v = v * (e / (e + 1.f));
                    Hs[(i * 16 + lg * 4 + r) * 136 + gc] = f2bf(v);
                }
        }
        __syncthreads();   // Hs ready

        #pragma unroll
        for (int ks = 0; ks < 4; ++ks) {
            short8 af[4];
            #pragma unroll
            for (int i = 0; i < 4; ++i)
                af[i] = *(const short8*)&Hs[(i * 16 + lr) * 136 + ks * 32 + lk];
            #pragma unroll
            for (int i = 0; i < 4; ++i)
                #pragma unroll
                for (int j = 0; j < 2; ++j)
                    acc[i][j] = __builtin_amdgcn_mfma_f32_16x16x32_bf16(
                                    af[i], w2f[j][ks], acc[i][j], 0, 0, 0);
        }
        __syncthreads();   // Hs consumed
    }

    #pragma unroll
    for (int j = 0; j < 2; ++j) {
        const int gc = wn * 32 + j * 16 + lr;
        const float bv = b2[gc];
        float s = 0.f, q = 0.f;
        #pragma unroll
        for (int i = 0; i < 4; ++i)
            #pragma unroll
            for (int r = 0; r < 4; ++r) {
                const int gr = i * 16 + lg * 4 + r;
                const float v = acc[i][j][r] + bv + bf2f(As[gr * 136 + gc]);
                acc[i][j][r] = v;
                s += v; q += v * v;
            }
        atomicAdd(&red[gc], s);
        atomicAdd(&red[128 + gc], q);
    }
    __syncthreads();
    if (t < 128) {
        atomicAdd(&stats[4096 + sh + t],       red[t]);
        atomicAdd(&stats[4096 + sh + 128 + t], red[128 + t]);
    }

    float* tr = (float*)pool;        // 128 x 68 fp32 = 34816 B
    #pragma unroll
    for (int j = 0; j < 2; ++j) {
        const int gc = wn * 32 + j * 16 + lr;
        #pragma unroll
        for (int i = 0; i < 4; ++i)
            #pragma unroll
            for (int r = 0; r < 4; ++r) {
                const int gr = i * 16 + lg * 4 + r;
                tr[gc * 68 + gr] = acc[i][j][r];
            }
    }
    __syncthreads();
    #pragma unroll
    for (int it = 0; it < 8; ++it) {
        const int idx = t + it * 256;
        const int c = idx >> 4, ch = (idx & 15) * 4;
        ushort4 o4;
        o4.x = f2bf(tr[c * 68 + ch + 0]);
        o4.y = f2bf(tr[c * 68 + ch + 1]);
        o4.z = f2bf(tr[c * 68 + ch + 2]);
        o4.w = f2bf(tr[c * 68 + ch + 3]);
        *(ushort4*)&tTb[(size_t)c * NPOS + n0 + ch] = o4;
    }
}

// ---------------------------------------------------------------------------
// K3: IN2 elementwise normalize, bf16 (C,N) in -> fp32 (C,N) out (R17 exact)
// ---------------------------------------------------------------------------
__global__ __launch_bounds__(256) void norm2_apply_kernel(
    const unsigned short* __restrict__ tTb, const float* __restrict__ stats,
    float* __restrict__ out)
{
    const int i = blockIdx.x * 256 + threadIdx.x;
    const size_t o = (size_t)i * 8;
    const int c = (int)(o >> 15);
    const float invN = 1.f / (float)NPOS;
    float s0 = 0.f, s1 = 0.f;
    #pragma unroll
    for (int s = 0; s < NSH; ++s) {
        s0 += stats[4096 + s * 256 + c];
        s1 += stats[4096 + s * 256 + 128 + c];
    }
    const float m  = s0 * invN;
    const float vr = s1 * invN - m * m;
    const float rs = rsqrtf(vr + 1e-5f);
    const uint4 raw = *(const uint4*)&tTb[o];
    const unsigned int u[4] = {raw.x, raw.y, raw.z, raw.w};
    float4 o0, o1;
    o0.x = (lo_bf(u[0]) - m) * rs; o0.y = (hi_bf(u[0]) - m) * rs;
    o0.z = (lo_bf(u[1]) - m) * rs; o0.w = (hi_bf(u[1]) - m) * rs;
    o1.x = (lo_bf(u[2]) - m) * rs; o1.y = (hi_bf(u[2]) - m) * rs;
    o1.z = (lo_bf(u[3]) - m) * rs; o1.w = (hi_bf(u[3]) - m) * rs;
    *(float4*)&out[o]     = o0;
    *(float4*)&out[o + 4] = o1;
}

// ---------------------------------------------------------------------------
extern "C" void kernel_launch(void* const* d_in, const int* in_sizes, int n_in,
                              void* d_out, int out_size, void* d_ws, size_t ws_size,
                              hipStream_t stream)
{
    const float* x      = (const float*)d_in[0];   // (128, 32768) = (C, N)
    const float* w_qkv  = (const float*)d_in[1];
    const float* b_qkv  = (const float*)d_in[2];
    const float* rpb    = (const float*)d_in[3];
    const float* w_proj = (const float*)d_in[4];
    const float* b_proj = (const float*)d_in[5];
    const float* w_ffn1 = (const float*)d_in[6];
    const float* b_ffn1 = (const float*)d_in[7];
    const float* w_ffn2 = (const float*)d_in[8];
    const float* b_ffn2 = (const float*)d_in[9];
    float* out = (float*)d_out;

    char* ws = (char*)d_ws;
    unsigned short* qkv_f16  = (unsigned short*)(ws + 8388608);    // 25.2 MB (head-major f16)
    unsigned short* attnO_bf = (unsigned short*)(ws + 33554432);   // 8.39 MB
    unsigned short* x5_bf    = (unsigned short*)(ws + 41943040);   // 8.39 MB
    unsigned short* tTb      = (unsigned short*)(ws + 50331648);   // 8.39 MB bf16
    unsigned short* wproj_bf = (unsigned short*)(ws + 83984384);
    unsigned short* wffn1_bf = (unsigned short*)(ws + 84017152);
    unsigned short* wffn2_bf = (unsigned short*)(ws + 84148224);
    float*          stats    = (float*)(ws + 84279296);            // 32 KB

    // 1) qkv fused: x-transpose staging + GEMM + weight-convert + stats-zero
    qkv_fused_kernel<<<dim3(C3 / 128, NPOS / 128), 256, 0, stream>>>(
        x, w_qkv, b_qkv, w_proj, w_ffn1, w_ffn2,
        wproj_bf, wffn1_bf, wffn2_bf, stats, qkv_f16);

    // 2) tiled neighborhood attention (packed-f16 math)
    attn_tiled<<<dim3(1024, 8), 256, 0, stream>>>(qkv_f16, rpb, attnO_bf);

    // 3) proj + IN1 stats (16-shadow atomics)
    proj_stats_kernel<<<NPOS / 64, 256, 0, stream>>>(
        attnO_bf, wproj_bf, b_proj, x5_bf, stats);

    // 4) IN1-normalize + FFN (rotated chunks) + residual + IN2 stats + transpose
    ffn_fused_kernel<<<NPOS / 64, 256, 0, stream>>>(
        x5_bf, wffn1_bf, b_ffn1, wffn2_bf, b_ffn2, stats, tTb);

    // 5) IN2 elementwise normalize (bf16 in, fp32 out)
    norm2_apply_kernel<<<(NPOS * CCH / 8) / 256, 256, 0, stream>>>(tTb, stats, out);
}

// Round 19
// 171.730 us; speedup vs baseline: 1.1155x; 1.0016x over previous
//
#include <hip/hip_runtime.h>
#include <hip/hip_bf16.h>
#include <hip/hip_fp16.h>
#include <math.h>

#define NPOS 32768      // 32*32*32
#define CCH  128
#define C3   384
#define CF   512
#define NSH  16         // stats shadow copies

typedef __attribute__((ext_vector_type(8))) short short8;
typedef __attribute__((ext_vector_type(4))) float f32x4;

__device__ inline float bf2f(unsigned short u) {
    union { unsigned int i; float f; } x; x.i = ((unsigned int)u) << 16; return x.f;
}
__device__ inline unsigned short f2bf(float f) {
    union { float f; unsigned int i; } x; x.f = f;
    unsigned int r = x.i + 0x7FFFu + ((x.i >> 16) & 1u);   // round-nearest-even
    return (unsigned short)(r >> 16);
}
__device__ inline float lo_bf(unsigned int u) {
    union { unsigned int i; float f; } x; x.i = u << 16; return x.f;
}
__device__ inline float hi_bf(unsigned int u) {
    union { unsigned int i; float f; } x; x.i = u & 0xffff0000u; return x.f;
}
__device__ inline unsigned short f2h(float f) {
    __half h = __float2half(f);
    return *reinterpret_cast<unsigned short*>(&h);
}

// ---------------------------------------------------------------------------
// qkv FUSED kernel: R18 + rotated B-staging order (decorrelates the 256-way
// same-line wqkv read storm across row-blocks; proven lever from R17 ffn).
// ---------------------------------------------------------------------------
__global__ __launch_bounds__(256) void qkv_fused_kernel(
    const float* __restrict__ x,        // (128, 32768) fp32
    const float* __restrict__ wqkv,     // (384, 128) fp32
    const float* __restrict__ b_qkv,
    const float* __restrict__ wp,  const float* __restrict__ w1f,
    const float* __restrict__ w2f,
    unsigned short* __restrict__ wp_b, unsigned short* __restrict__ w1_b,
    unsigned short* __restrict__ w2_b,
    float* __restrict__ stats,
    unsigned short* __restrict__ outh)  // (24, N, 16) F16 head-major
{
    __shared__ alignas(16) unsigned short As[128 * 136];   // [n][c] bf16
    __shared__ alignas(16) unsigned short Bs[128 * 136];   // [col][c] bf16

    const int tid  = threadIdx.x;
    const int lane = tid & 63;
    const int wave = tid >> 6;
    const int wm = wave & 1, wn = wave >> 1;
    const int row0 = blockIdx.y * 128;
    const int col0 = blockIdx.x * 128;
    const int rot  = blockIdx.y & 15;

    if (blockIdx.x == 0) {
        if (blockIdx.y < 16) {
            stats[blockIdx.y * 512 + tid] = 0.f;
            stats[blockIdx.y * 512 + 256 + tid] = 0.f;
        }
        if (tid < 144) {
            const int ci = blockIdx.y * 144 + tid;   // 0..36863 float4s
            const float* src; unsigned short* dst; int off;
            if (ci < 4096)       { src = wp;  dst = wp_b; off = ci; }
            else if (ci < 20480) { src = w1f; dst = w1_b; off = ci - 4096; }
            else                 { src = w2f; dst = w2_b; off = ci - 20480; }
            const float4 v = ((const float4*)src)[off];
            ushort4 o;
            o.x = f2bf(v.x); o.y = f2bf(v.y); o.z = f2bf(v.z); o.w = f2bf(v.w);
            ((ushort4*)dst)[off] = o;
        }
    }

    #pragma unroll
    for (int it = 0; it < 16; ++it) {
        const int idx = tid + it * 256;
        const int c  = idx >> 5;
        const int nq = idx & 31;
        const float4 v = *(const float4*)&x[(size_t)c * NPOS + row0 + nq * 4];
        As[(nq * 4 + 0) * 136 + c] = f2bf(v.x);
        As[(nq * 4 + 1) * 136 + c] = f2bf(v.y);
        As[(nq * 4 + 2) * 136 + c] = f2bf(v.z);
        As[(nq * 4 + 3) * 136 + c] = f2bf(v.w);
    }
    #pragma unroll
    for (int it = 0; it < 16; ++it) {
        const int itr = (it + rot) & 15;          // rotated issue order
        const int idx = tid + itr * 256;
        const int col = idx >> 5;
        const int cq  = idx & 31;
        const float4 v = *(const float4*)&wqkv[(size_t)(col0 + col) * CCH + cq * 4];
        ushort4 o;
        o.x = f2bf(v.x); o.y = f2bf(v.y); o.z = f2bf(v.z); o.w = f2bf(v.w);
        *(ushort4*)&Bs[col * 136 + cq * 4] = o;
    }
    __syncthreads();

    const f32x4 fzero = {0.f, 0.f, 0.f, 0.f};
    f32x4 acc[4][4];
    #pragma unroll
    for (int i = 0; i < 4; ++i)
        #pragma unroll
        for (int j = 0; j < 4; ++j) acc[i][j] = fzero;

    const int lr = lane & 15;
    const int lk = (lane >> 4) * 8;

    #pragma unroll
    for (int ks = 0; ks < 4; ++ks) {
        short8 af[4], bfr[4];
        #pragma unroll
        for (int i = 0; i < 4; ++i)
            af[i]  = *(const short8*)&As[(wm * 64 + i * 16 + lr) * 136 + ks * 32 + lk];
        #pragma unroll
        for (int j = 0; j < 4; ++j)
            bfr[j] = *(const short8*)&Bs[(wn * 64 + j * 16 + lr) * 136 + ks * 32 + lk];
        #pragma unroll
        for (int i = 0; i < 4; ++i)
            #pragma unroll
            for (int j = 0; j < 4; ++j)
                acc[i][j] = __builtin_amdgcn_mfma_f32_16x16x32_bf16(
                                af[i], bfr[j], acc[i][j], 0, 0, 0);
    }

    const int gr0 = row0 + wm * 64 + (lane >> 4) * 4;
    const int gc0 = col0 + wn * 64 + lr;
    #pragma unroll
    for (int j = 0; j < 4; ++j) {
        const int gc  = gc0 + j * 16;
        const int sel = gc >> 4;
        const int ch  = gc & 15;
        const float bv = b_qkv[gc];
        #pragma unroll
        for (int i = 0; i < 4; ++i) {
            #pragma unroll
            for (int r = 0; r < 4; ++r) {
                const int gr = gr0 + i * 16 + r;
                outh[((size_t)sel * NPOS + gr) * 16 + ch] = f2h(acc[i][j][r] + bv);
            }
        }
    }
}

// ---------------------------------------------------------------------------
// Tiled neighborhood attention (packed f16). THIS ROUND: logits stored as
// PRE-PACKED half2(e,e) at softmax-write time -> PV inner loop is pure
// {LDS read, LDS read, hfma2}, no cvt (bit-identical math to R18).
// ---------------------------------------------------------------------------
__global__ __launch_bounds__(256) void attn_tiled(
    const unsigned short* __restrict__ qkv,   // (24, N, 16) f16 head-major
    const float* __restrict__ rpb,
    unsigned short* __restrict__ out)         // (N,128) bf16
{
    __shared__ unsigned int ksu[288 * 8];
    __shared__ unsigned int vsu[288 * 8];
    __shared__ unsigned int qsu[32 * 8];
    __shared__ unsigned int logits[32 * 29];  // packed half2(e,e)
    __shared__ float rpbs[125];
    __shared__ float sinv[32];

    const int t  = threadIdx.x;
    const int line = ((blockIdx.x & 7) << 7) + (blockIdx.x >> 3);
    const int h  = blockIdx.y;
    const int w0 = line & 31, h0 = line >> 5;
    const int n0 = (h0 << 10) + (w0 << 5);
    const int sh0 = min(max(h0 - 1, 0), 29);
    const int sw0 = min(max(w0 - 1, 0), 29);
    const int rh_off = sh0 - h0 + 2;
    const int rw_off = sw0 - w0 + 2;

    if (t < 64) {
        const int pos = t >> 1, part = t & 1;
        const uint4 raw = *(const uint4*)&qkv[((size_t)h * NPOS + n0 + pos) * 16 + part * 8];
        *(uint4*)&qsu[pos * 8 + part * 4] = raw;
    } else if (t < 192) {
        const int i = t - 64;
        if (i < 125) rpbs[i] = rpb[h * 125 + i];
    }
    for (int c = t; c < 1152; c += 256) {
        const int p = c >> 2, part = c & 3;
        const int ihw = p >> 5, z = p & 31;
        const int ih = (ihw * 11) >> 5;
        const int iw = ihw - 3 * ih;
        const int n = ((sh0 + ih) << 10) + ((sw0 + iw) << 5) + z;
        const int kv = part >> 1;              // 0 = K, 1 = V
        const uint4 raw = *(const uint4*)&qkv[((size_t)(8 + kv * 8 + h) * NPOS + n) * 16
                                              + (part & 1) * 8];
        unsigned int* d = ((kv == 0) ? ksu : vsu) + p * 8 + (part & 1) * 4;
        *(uint4*)d = raw;
    }
    __syncthreads();

    // ---- QK^T (packed f16) + wave-parallel softmax : thread = (query, j)
    {
        const int q = t >> 3, j = t & 7;
        const int sz = min(max(q - 1, 0), 29);
        const int rz_off = sz - q + 2;
        __half2 qh[8];
        #pragma unroll
        for (int d2 = 0; d2 < 8; ++d2)
            qh[d2] = *(const __half2*)&qsu[q * 8 + d2];
        float lv[4];
        int nkk = 0;
        for (int kk = j; kk < 27; kk += 8) {
            const int ihw = kk / 3, dz = kk - 3 * ihw;
            const int ih = ihw / 3,  iw = ihw - 3 * ih;
            const int p = ihw * 32 + sz + dz;
            __half2 acc2 = __float2half2_rn(0.f);
            #pragma unroll
            for (int d2 = 0; d2 < 8; ++d2)
                acc2 = __hfma2(qh[d2], *(const __half2*)&ksu[p * 8 + d2], acc2);
            const float2 f2 = __half22float2(acc2);
            const float a = f2.x + f2.y;
            const int bidx = ((ih + rh_off) * 5 + (iw + rw_off)) * 5 + (dz + rz_off);
            lv[nkk++] = a * 0.25f + rpbs[bidx];
        }
        float mx = -1e30f;
        #pragma unroll
        for (int u = 0; u < 4; ++u) if (u < nkk) mx = fmaxf(mx, lv[u]);
        mx = fmaxf(mx, __shfl_xor(mx, 1));
        mx = fmaxf(mx, __shfl_xor(mx, 2));
        mx = fmaxf(mx, __shfl_xor(mx, 4));
        float s = 0.f;
        int u = 0;
        for (int kk = j; kk < 27; kk += 8) {
            const float e = __expf(lv[u++] - mx);
            const __half2 e2 = __float2half2_rn(e);      // pack once here
            logits[q * 29 + kk] = *reinterpret_cast<const unsigned int*>(&e2);
            s += e;
        }
        s += __shfl_xor(s, 1);
        s += __shfl_xor(s, 2);
        s += __shfl_xor(s, 4);
        if (j == 0) sinv[q] = 1.f / s;
    }
    __syncthreads();

    // ---- PV (packed f16, cvt-free inner loop): thread = (query, dim-pair)
    {
        const int q = t >> 3, d2 = t & 7;
        const int sz = min(max(q - 1, 0), 29);
        __half2 acc2 = __float2half2_rn(0.f);
        #pragma unroll
        for (int kk = 0; kk < 27; ++kk) {
            const int p = (kk / 3) * 32 + sz + (kk % 3);
            acc2 = __hfma2(*(const __half2*)&logits[q * 29 + kk],
                           *(const __half2*)&vsu[p * 8 + d2], acc2);
        }
        const float2 f2 = __half22float2(acc2);
        const float inv = sinv[q];
        const unsigned int o = ((unsigned int)f2bf(f2.y * inv) << 16)
                             |  (unsigned int)f2bf(f2.x * inv);
        *(unsigned int*)&out[(size_t)(n0 + q) * CCH + h * 16 + d2 * 2] = o;
    }
}

// ---------------------------------------------------------------------------
// K1: proj GEMM (K=128) + bias -> x5 (bf16) + IN1 stats (16-shadow banks)
// (R17 exact)
// ---------------------------------------------------------------------------
__global__ __launch_bounds__(256) void proj_stats_kernel(
    const unsigned short* __restrict__ attnO,   // (N,128) bf16
    const unsigned short* __restrict__ wproj,   // (128,128) bf16
    const float* __restrict__ b_proj,
    unsigned short* __restrict__ x5b,           // (N,128) bf16 out
    float* __restrict__ stats)                  // [s*256 + {c,128+c}], s<16 : IN1
{
    __shared__ float red[256];

    const int t    = threadIdx.x;
    const int lane = t & 63;
    const int wn   = t >> 6;
    const int lr = lane & 15;
    const int lg = lane >> 4;
    const int lk = lg * 8;
    const int n0 = blockIdx.x * 64;
    const int sh = (blockIdx.x & (NSH - 1)) * 256;

    red[t] = 0.f;

    short8 wf[2][4];
    #pragma unroll
    for (int j = 0; j < 2; ++j)
        #pragma unroll
        for (int ks = 0; ks < 4; ++ks)
            wf[j][ks] = *(const short8*)&wproj[(wn * 32 + j * 16 + lr) * CCH + ks * 32 + lk];

    const f32x4 fzero = {0.f, 0.f, 0.f, 0.f};
    f32x4 acc[4][2];
    #pragma unroll
    for (int i = 0; i < 4; ++i)
        #pragma unroll
        for (int j = 0; j < 2; ++j) acc[i][j] = fzero;

    #pragma unroll
    for (int ks = 0; ks < 4; ++ks) {
        short8 af[4];
        #pragma unroll
        for (int i = 0; i < 4; ++i)
            af[i] = *(const short8*)&attnO[(size_t)(n0 + i * 16 + lr) * CCH + ks * 32 + lk];
        #pragma unroll
        for (int i = 0; i < 4; ++i)
            #pragma unroll
            for (int j = 0; j < 2; ++j)
                acc[i][j] = __builtin_amdgcn_mfma_f32_16x16x32_bf16(
                                af[i], wf[j][ks], acc[i][j], 0, 0, 0);
    }
    __syncthreads();   // red[] zeroed before atomics

    #pragma unroll
    for (int j = 0; j < 2; ++j) {
        const int gc = wn * 32 + j * 16 + lr;
        const float bv = b_proj[gc];
        float s = 0.f, q = 0.f;
        #pragma unroll
        for (int i = 0; i < 4; ++i)
            #pragma unroll
            for (int r = 0; r < 4; ++r) {
                const int gr = i * 16 + lg * 4 + r;
                const float v = acc[i][j][r] + bv;
                s += v; q += v * v;
                x5b[(size_t)(n0 + gr) * CCH + gc] = f2bf(v);
            }
        atomicAdd(&red[gc], s);
        atomicAdd(&red[128 + gc], q);
    }
    __syncthreads();
    if (t < 128) {
        atomicAdd(&stats[sh + t],       red[t]);
        atomicAdd(&stats[sh + 128 + t], red[128 + t]);
    }
}

// ---------------------------------------------------------------------------
// K2: IN1-normalize -> FFN (4 chunks, per-block ROTATED order) -> +residual
//     -> IN2 stats (16-shadow) -> transpose -> tTb (C,N) bf16. (R17 exact)
// ---------------------------------------------------------------------------
__global__ __launch_bounds__(256) void ffn_fused_kernel(
    const unsigned short* __restrict__ x5b,     // (N,128) bf16
    const unsigned short* __restrict__ w1,      // (512,128) bf16
    const float* __restrict__ b1,
    const unsigned short* __restrict__ w2,      // (128,512) bf16
    const float* __restrict__ b2,
    float* __restrict__ stats,                  // [0:4096) IN1 shadows, [4096:8192) IN2
    unsigned short* __restrict__ tTb)           // (128, 32768) bf16 out
{
    __shared__ alignas(16) unsigned short pool[2 * 8704];   // As | Hs
    unsigned short* As = pool;
    unsigned short* Hs = pool + 8704;
    __shared__ float red[256];
    __shared__ float ms[128];
    __shared__ float rss[128];

    const int t    = threadIdx.x;
    const int lane = t & 63;
    const int wn   = t >> 6;
    const int lr = lane & 15;
    const int lg = lane >> 4;
    const int lk = lg * 8;
    const int n0 = blockIdx.x * 64;
    const int sh = (blockIdx.x & (NSH - 1)) * 256;
    const int crot = blockIdx.x & 3;             // per-block chunk rotation
    const float invN = 1.f / (float)NPOS;
    const f32x4 fzero = {0.f, 0.f, 0.f, 0.f};

    red[t] = 0.f;
    if (t < 128) {
        float s0 = 0.f, s1 = 0.f;
        #pragma unroll
        for (int s = 0; s < NSH; ++s) {
            s0 += stats[s * 256 + t];
            s1 += stats[s * 256 + 128 + t];
        }
        const float m = s0 * invN;
        const float v = s1 * invN - m * m;
        ms[t]  = m;
        rss[t] = rsqrtf(v + 1e-5f);
    }
    uint4 px[4];
    #pragma unroll
    for (int it = 0; it < 4; ++it) {
        const int idx = t + it * 256;
        const int row = idx >> 4, c0 = (idx & 15) * 8;
        px[it] = *(const uint4*)&x5b[(size_t)(n0 + row) * CCH + c0];
    }
    __syncthreads();

    #pragma unroll
    for (int it = 0; it < 4; ++it) {
        const int idx = t + it * 256;
        const int row = idx >> 4, c0 = (idx & 15) * 8;
        unsigned int u[4] = {px[it].x, px[it].y, px[it].z, px[it].w};
        #pragma unroll
        for (int p = 0; p < 4; ++p) {
            const int c = c0 + 2 * p;
            const float a = (lo_bf(u[p]) - ms[c])     * rss[c];
            const float b = (hi_bf(u[p]) - ms[c + 1]) * rss[c + 1];
            u[p] = ((unsigned int)f2bf(b) << 16) | (unsigned int)f2bf(a);
        }
        uint4 w; w.x = u[0]; w.y = u[1]; w.z = u[2]; w.w = u[3];
        *(uint4*)&As[row * 136 + c0] = w;
    }
    __syncthreads();

    f32x4 acc[4][2];
    #pragma unroll
    for (int i = 0; i < 4; ++i)
        #pragma unroll
        for (int j = 0; j < 2; ++j) acc[i][j] = fzero;

    #pragma unroll 1
    for (int cc = 0; cc < 4; ++cc) {
        const int ccp = (cc + crot) & 3;         // rotated chunk index

        short8 w1f[2][4];
        #pragma unroll
        for (int j = 0; j < 2; ++j)
            #pragma unroll
            for (int ks = 0; ks < 4; ++ks)
                w1f[j][ks] = *(const short8*)&w1[
                    (size_t)(ccp * 128 + wn * 32 + j * 16 + lr) * CCH + ks * 32 + lk];

        f32x4 hacc[4][2];
        #pragma unroll
        for (int i = 0; i < 4; ++i)
            #pragma unroll
            for (int j = 0; j < 2; ++j) hacc[i][j] = fzero;
        #pragma unroll
        for (int ks = 0; ks < 4; ++ks) {
            short8 af[4];
            #pragma unroll
            for (int i = 0; i < 4; ++i)
                af[i] = *(const short8*)&As[(i * 16 + lr) * 136 + ks * 32 + lk];
            #pragma unroll
            for (int i = 0; i < 4; ++i)
                #pragma unroll
                for (int j = 0; j < 2; ++j)
                    hacc[i][j] = __builtin_amdgcn_mfma_f32_16x16x32_bf16(
                                    af[i], w1f[j][ks], hacc[i][j], 0, 0, 0);
        }

        short8 w2f[2][4];
        #pragma unroll
        for (int j = 0; j < 2; ++j)
            #pragma unroll
            for (int ks = 0; ks < 4; ++ks)
                w2f[j][ks] = *(const short8*)&w2[
                    (size_t)(wn * 32 + j * 16 + lr) * CF + ccp * 128 + ks * 32 + lk];

        #pragma unroll
        for (int j = 0; j < 2; ++j) {
            const int gc = wn * 32 + j * 16 + lr;
            const float bv = b1[ccp * 128 + gc];
            #pragma unroll
            for (int i = 0; i < 4; ++i)
                #pragma unroll
                for (int r = 0; r < 4; ++r) {
                    float v = hacc[i][j][r] + bv;
                    const float g = 0.7978845608028654f * (v + 0.044715f * v * v * v);
                    const float e = __expf(2.f * g);
                    v = v * (e / (e + 1.f));
                    Hs[(i * 16 + lg * 4 + r) * 136 + gc] = f2bf(v);
                }
        }
        __syncthreads();   // Hs ready

        #pragma unroll
        for (int ks = 0; ks < 4; ++ks) {
            short8 af[4];
            #pragma unroll
            for (int i = 0; i < 4; ++i)
                af[i] = *(const short8*)&Hs[(i * 16 + lr) * 136 + ks * 32 + lk];
            #pragma unroll
            for (int i = 0; i < 4; ++i)
                #pragma unroll
                for (int j = 0; j < 2; ++j)
                    acc[i][j] = __builtin_amdgcn_mfma_f32_16x16x32_bf16(
                                    af[i], w2f[j][ks], acc[i][j], 0, 0, 0);
        }
        __syncthreads();   // Hs consumed
    }

    #pragma unroll
    for (int j = 0; j < 2; ++j) {
        const int gc = wn * 32 + j * 16 + lr;
        const float bv = b2[gc];
        float s = 0.f, q = 0.f;
        #pragma unroll
        for (int i = 0; i < 4; ++i)
            #pragma unroll
            for (int r = 0; r < 4; ++r) {
                const int gr = i * 16 + lg * 4 + r;
                const float v = acc[i][j][r] + bv + bf2f(As[gr * 136 + gc]);
                acc[i][j][r] = v;
                s += v; q += v * v;
            }
        atomicAdd(&red[gc], s);
        atomicAdd(&red[128 + gc], q);
    }
    __syncthreads();
    if (t < 128) {
        atomicAdd(&stats[4096 + sh + t],       red[t]);
        atomicAdd(&stats[4096 + sh + 128 + t], red[128 + t]);
    }

    float* tr = (float*)pool;        // 128 x 68 fp32 = 34816 B
    #pragma unroll
    for (int j = 0; j < 2; ++j) {
        const int gc = wn * 32 + j * 16 + lr;
        #pragma unroll
        for (int i = 0; i < 4; ++i)
            #pragma unroll
            for (int r = 0; r < 4; ++r) {
                const int gr = i * 16 + lg * 4 + r;
                tr[gc * 68 + gr] = acc[i][j][r];
            }
    }
    __syncthreads();
    #pragma unroll
    for (int it = 0; it < 8; ++it) {
        const int idx = t + it * 256;
        const int c = idx >> 4, ch = (idx & 15) * 4;
        ushort4 o4;
        o4.x = f2bf(tr[c * 68 + ch + 0]);
        o4.y = f2bf(tr[c * 68 + ch + 1]);
        o4.z = f2bf(tr[c * 68 + ch + 2]);
        o4.w = f2bf(tr[c * 68 + ch + 3]);
        *(ushort4*)&tTb[(size_t)c * NPOS + n0 + ch] = o4;
    }
}

// ---------------------------------------------------------------------------
// K3: IN2 elementwise normalize, bf16 (C,N) in -> fp32 (C,N) out (R17 exact)
// ---------------------------------------------------------------------------
__global__ __launch_bounds__(256) void norm2_apply_kernel(
    const unsigned short* __restrict__ tTb, const float* __restrict__ stats,
    float* __restrict__ out)
{
    const int i = blockIdx.x * 256 + threadIdx.x;
    const size_t o = (size_t)i * 8;
    const int c = (int)(o >> 15);
    const float invN = 1.f / (float)NPOS;
    float s0 = 0.f, s1 = 0.f;
    #pragma unroll
    for (int s = 0; s < NSH; ++s) {
        s0 += stats[4096 + s * 256 + c];
        s1 += stats[4096 + s * 256 + 128 + c];
    }
    const float m  = s0 * invN;
    const float vr = s1 * invN - m * m;
    const float rs = rsqrtf(vr + 1e-5f);
    const uint4 raw = *(const uint4*)&tTb[o];
    const unsigned int u[4] = {raw.x, raw.y, raw.z, raw.w};
    float4 o0, o1;
    o0.x = (lo_bf(u[0]) - m) * rs; o0.y = (hi_bf(u[0]) - m) * rs;
    o0.z = (lo_bf(u[1]) - m) * rs; o0.w = (hi_bf(u[1]) - m) * rs;
    o1.x = (lo_bf(u[2]) - m) * rs; o1.y = (hi_bf(u[2]) - m) * rs;
    o1.z = (lo_bf(u[3]) - m) * rs; o1.w = (hi_bf(u[3]) - m) * rs;
    *(float4*)&out[o]     = o0;
    *(float4*)&out[o + 4] = o1;
}

// ---------------------------------------------------------------------------
extern "C" void kernel_launch(void* const* d_in, const int* in_sizes, int n_in,
                              void* d_out, int out_size, void* d_ws, size_t ws_size,
                              hipStream_t stream)
{
    const float* x      = (const float*)d_in[0];   // (128, 32768) = (C, N)
    const float* w_qkv  = (const float*)d_in[1];
    const float* b_qkv  = (const float*)d_in[2];
    const float* rpb    = (const float*)d_in[3];
    const float* w_proj = (const float*)d_in[4];
    const float* b_proj = (const float*)d_in[5];
    const float* w_ffn1 = (const float*)d_in[6];
    const float* b_ffn1 = (const float*)d_in[7];
    const float* w_ffn2 = (const float*)d_in[8];
    const float* b_ffn2 = (const float*)d_in[9];
    float* out = (float*)d_out;

    char* ws = (char*)d_ws;
    unsigned short* qkv_f16  = (unsigned short*)(ws + 8388608);    // 25.2 MB (head-major f16)
    unsigned short* attnO_bf = (unsigned short*)(ws + 33554432);   // 8.39 MB
    unsigned short* x5_bf    = (unsigned short*)(ws + 41943040);   // 8.39 MB
    unsigned short* tTb      = (unsigned short*)(ws + 50331648);   // 8.39 MB bf16
    unsigned short* wproj_bf = (unsigned short*)(ws + 83984384);
    unsigned short* wffn1_bf = (unsigned short*)(ws + 84017152);
    unsigned short* wffn2_bf = (unsigned short*)(ws + 84148224);
    float*          stats    = (float*)(ws + 84279296);            // 32 KB

    // 1) qkv fused (rotated wqkv staging)
    qkv_fused_kernel<<<dim3(C3 / 128, NPOS / 128), 256, 0, stream>>>(
        x, w_qkv, b_qkv, w_proj, w_ffn1, w_ffn2,
        wproj_bf, wffn1_bf, wffn2_bf, stats, qkv_f16);

    // 2) tiled neighborhood attention (packed-f16, cvt-free PV)
    attn_tiled<<<dim3(1024, 8), 256, 0, stream>>>(qkv_f16, rpb, attnO_bf);

    // 3) proj + IN1 stats (16-shadow atomics)
    proj_stats_kernel<<<NPOS / 64, 256, 0, stream>>>(
        attnO_bf, wproj_bf, b_proj, x5_bf, stats);

    // 4) IN1-normalize + FFN (rotated chunks) + residual + IN2 stats + transpose
    ffn_fused_kernel<<<NPOS / 64, 256, 0, stream>>>(
        x5_bf, wffn1_bf, b_ffn1, wffn2_bf, b_ffn2, stats, tTb);

    // 5) IN2 elementwise normalize (bf16 in, fp32 out)
    norm2_apply_kernel<<<(NPOS * CCH / 8) / 256, 256, 0, stream>>>(tTb, stats, out);
}